// Round 2
// baseline (15018.039 us; speedup 1.0000x reference)
//
#include <hip/hip_runtime.h>
#include <math.h>

// Problem constants
#define BN   128      // batch
#define CIN  3
#define HCn  32       // hidden channels (ODE state)
#define HHCn 128      // inner hidden channels
#define NPX  1024     // 32*32
#define PN   4        // pieces
#define NCLS 10

__device__ __forceinline__ float softplus_f(float x) {
    return fmaxf(x, 0.f) + log1pf(expf(-fabsf(x)));
}

// ---------------- augment: z = x * aug_W^T + aug_b  (1x1 conv 3->32) ----------------
__global__ __launch_bounds__(256) void k_aug(
    const float* __restrict__ x, const float* __restrict__ aW,
    const float* __restrict__ ab, float* __restrict__ z)
{
    const int b = blockIdx.x, tid = threadIdx.x;
    const size_t xb = (size_t)b * CIN * NPX;
    const size_t zb = (size_t)b * HCn * NPX;
    float xv[CIN][4];
#pragma unroll
    for (int c = 0; c < CIN; c++)
#pragma unroll
        for (int j = 0; j < 4; j++)
            xv[c][j] = x[xb + c * NPX + tid + 256 * j];
    for (int o = 0; o < HCn; o++) {
        float w0 = aW[o * 3], w1 = aW[o * 3 + 1], w2 = aW[o * 3 + 2], bb = ab[o];
#pragma unroll
        for (int j = 0; j < 4; j++) {
            float v = fmaf(w0, xv[0][j], fmaf(w1, xv[1][j], fmaf(w2, xv[2][j], bb)));
            z[zb + (size_t)o * NPX + tid + 256 * j] = v;
        }
    }
}

// ---------------- conv1: h1 = softplus(W1 * [t ; (z + alpha*k)] + b1) ----------------
// grid (8, B), 256 thr; 16 oc x 4 px per thread
__global__ __launch_bounds__(256) void k_conv1(
    const float* __restrict__ z, const float* __restrict__ kb, float alpha,
    const float* __restrict__ W1p, const float* __restrict__ b1p, float t,
    float* __restrict__ h1)
{
    const int b = blockIdx.y, ocg = blockIdx.x, tid = threadIdx.x;
    const int oc0 = ocg * 16;
    float acc[16][4];
#pragma unroll
    for (int o = 0; o < 16; o++) {
        float eb = b1p[oc0 + o] + t * W1p[(oc0 + o) * 33];   // t-channel folded into bias
#pragma unroll
        for (int j = 0; j < 4; j++) acc[o][j] = eb;
    }
    const size_t zb = (size_t)b * HCn * NPX;
    for (int ic = 0; ic < HCn; ic++) {
        float inv[4];
#pragma unroll
        for (int j = 0; j < 4; j++) {
            size_t idx = zb + (size_t)ic * NPX + tid + 256 * j;
            float v = z[idx];
            if (alpha != 0.f) v = fmaf(alpha, kb[idx], v);
            inv[j] = v;
        }
#pragma unroll
        for (int o = 0; o < 16; o++) {
            float w = W1p[(oc0 + o) * 33 + 1 + ic];
#pragma unroll
            for (int j = 0; j < 4; j++) acc[o][j] = fmaf(w, inv[j], acc[o][j]);
        }
    }
    const size_t hb = (size_t)b * HHCn * NPX;
#pragma unroll
    for (int o = 0; o < 16; o++)
#pragma unroll
        for (int j = 0; j < 4; j++)
            h1[hb + (size_t)(oc0 + o) * NPX + tid + 256 * j] = softplus_f(acc[o][j]);
}

// ---------------- conv3x3: h2 = softplus(conv3x3(h1, W2) + b2) ----------------
// grid (4, B), 256 thr; 32 oc x 4 px per thread; 8 input planes per LDS stage.
// Staging index math hoisted out of the stage loop (stage-invariant mapping).
#define PLANE 1156   // 34*34
__global__ __launch_bounds__(256, 2) void k_conv3(
    const float* __restrict__ h1, const float* __restrict__ W2p,
    const float* __restrict__ b2p, float* __restrict__ h2)
{
    const int b = blockIdx.y, ocg = blockIdx.x, tid = threadIdx.x;
    const int oc0 = ocg * 32;
    __shared__ float lds[8 * PLANE];   // 8 planes of 34x34 zero-padded, 37 KB

    // hoisted staging map: slot it -> (valid?, source offset)
    int srcoff[5]; bool ok[5];
#pragma unroll
    for (int it = 0; it < 5; it++) {
        int i = tid + 256 * it;
        int yy = i / 34, xx = i - yy * 34;
        ok[it] = (i < PLANE) && yy >= 1 && yy <= 32 && xx >= 1 && xx <= 32;
        srcoff[it] = (yy - 1) * 32 + (xx - 1);
    }

    float acc[32][4];
#pragma unroll
    for (int o = 0; o < 32; o++) {
        float bb = b2p[oc0 + o];
#pragma unroll
        for (int j = 0; j < 4; j++) acc[o][j] = bb;
    }
    int base[4];
#pragma unroll
    for (int j = 0; j < 4; j++) {
        int p = tid + 256 * j;
        base[j] = (p >> 5) * 34 + (p & 31);   // top-left of 3x3 window in padded plane
    }
    const size_t hb = (size_t)b * HHCn * NPX;

    for (int s = 0; s < 16; s++) {            // 8 input channels per stage
        __syncthreads();
#pragma unroll
        for (int ic = 0; ic < 8; ic++) {
            const float* src = h1 + hb + (size_t)(s * 8 + ic) * NPX;
#pragma unroll
            for (int it = 0; it < 5; it++) {
                int i = tid + 256 * it;
                if (i < PLANE) {
                    float v = 0.f;
                    if (ok[it]) v = src[srcoff[it]];
                    lds[ic * PLANE + i] = v;
                }
            }
        }
        __syncthreads();
#pragma unroll 1
        for (int ic = 0; ic < 8; ic++) {
            const int icg = s * 8 + ic;
            const float* wrow = W2p + ((size_t)oc0 * HHCn + icg) * 9;
#pragma unroll
            for (int dy = 0; dy < 3; dy++)
#pragma unroll
            for (int dx = 0; dx < 3; dx++) {
                float inv[4];
#pragma unroll
                for (int j = 0; j < 4; j++)
                    inv[j] = lds[ic * PLANE + base[j] + dy * 34 + dx];
#pragma unroll
                for (int o = 0; o < 32; o++) {
                    float w = wrow[(size_t)o * HHCn * 9 + dy * 3 + dx];
#pragma unroll
                    for (int j = 0; j < 4; j++) acc[o][j] = fmaf(w, inv[j], acc[o][j]);
                }
            }
        }
    }
    const size_t ob = (size_t)b * HHCn * NPX;
#pragma unroll
    for (int o = 0; o < 32; o++)
#pragma unroll
        for (int j = 0; j < 4; j++)
            h2[ob + (size_t)(oc0 + o) * NPX + tid + 256 * j] = softplus_f(acc[o][j]);
}

// ---------------- convw3: k = tanh(W3*h2 + b3), fused RK4 accumulation ----------------
// mode 0: k=v, acc=v      (k1)
// mode 1: k=v, acc+=2v    (k2,k3)
// mode 2: z += (acc+v)/6  (k4)
// grid (2, B), 256 thr; 16 oc x 4 px per thread
__global__ __launch_bounds__(256) void k_convw3(
    const float* __restrict__ h2, const float* __restrict__ W3p,
    const float* __restrict__ b3p, float* __restrict__ kb,
    float* __restrict__ accb, float* __restrict__ zb_, int mode)
{
    const int b = blockIdx.y, ocg = blockIdx.x, tid = threadIdx.x;
    const int oc0 = ocg * 16;
    float acc[16][4];
#pragma unroll
    for (int o = 0; o < 16; o++) {
        float eb = b3p[oc0 + o];
#pragma unroll
        for (int j = 0; j < 4; j++) acc[o][j] = eb;
    }
    const size_t hb = (size_t)b * HHCn * NPX;
    for (int ic = 0; ic < HHCn; ic++) {
        float inv[4];
#pragma unroll
        for (int j = 0; j < 4; j++)
            inv[j] = h2[hb + (size_t)ic * NPX + tid + 256 * j];
#pragma unroll
        for (int o = 0; o < 16; o++) {
            float w = W3p[(oc0 + o) * HHCn + ic];
#pragma unroll
            for (int j = 0; j < 4; j++) acc[o][j] = fmaf(w, inv[j], acc[o][j]);
        }
    }
    const size_t ob = (size_t)b * HCn * NPX;
#pragma unroll
    for (int o = 0; o < 16; o++)
#pragma unroll
        for (int j = 0; j < 4; j++) {
            float v = tanhf(acc[o][j]);
            size_t i = ob + (size_t)(oc0 + o) * NPX + tid + 256 * j;
            if (mode == 0)      { kb[i] = v; accb[i] = v; }
            else if (mode == 1) { kb[i] = v; accb[i] += 2.f * v; }
            else                { zb_[i] += (accb[i] + v) * (1.f / 6.f); }
        }
}

// ---------------- readout: logits[b][c] = z_flat[b] . ro_W[c] + ro_b[c] ----------------
__global__ __launch_bounds__(256) void k_logits(
    const float* __restrict__ z, const float* __restrict__ roW,
    const float* __restrict__ rob, float* __restrict__ logits)
{
    const int b = blockIdx.x, tid = threadIdx.x;
    float p[NCLS];
#pragma unroll
    for (int c = 0; c < NCLS; c++) p[c] = 0.f;
    const float* zp = z + (size_t)b * 32768;
    for (int i = tid; i < 32768; i += 256) {
        float zv = zp[i];
#pragma unroll
        for (int c = 0; c < NCLS; c++) p[c] = fmaf(zv, roW[(size_t)c * 32768 + i], p[c]);
    }
#pragma unroll
    for (int c = 0; c < NCLS; c++)
        for (int off = 32; off > 0; off >>= 1) p[c] += __shfl_down(p[c], off, 64);
    __shared__ float red[4][NCLS];
    int wid = tid >> 6, lane = tid & 63;
    if (lane == 0)
#pragma unroll
        for (int c = 0; c < NCLS; c++) red[wid][c] = p[c];
    __syncthreads();
    if (tid < NCLS) {
        float s = red[0][tid] + red[1][tid] + red[2][tid] + red[3][tid] + rob[tid];
        logits[b * NCLS + tid] = s;
    }
}

// ---------------- loss + accuracy ----------------
__global__ __launch_bounds__(128) void k_loss(
    const float* __restrict__ logits, const int* __restrict__ y,
    float* __restrict__ out)
{
    const int b = threadIdx.x;   // 0..127
    float l[NCLS];
#pragma unroll
    for (int c = 0; c < NCLS; c++) l[c] = logits[b * NCLS + c];
    float m = l[0]; int am = 0;
#pragma unroll
    for (int c = 1; c < NCLS; c++) if (l[c] > m) { m = l[c]; am = c; }
    float s = 0.f;
#pragma unroll
    for (int c = 0; c < NCLS; c++) s += expf(l[c] - m);
    float lse = m + logf(s);
    int yy = y[b];
    float loss_b = lse - l[yy];
    float corr = (am == yy) ? 1.f : 0.f;
    for (int off = 32; off > 0; off >>= 1) {
        loss_b += __shfl_down(loss_b, off, 64);
        corr   += __shfl_down(corr,   off, 64);
    }
    __shared__ float sl[2], sc[2];
    if ((b & 63) == 0) { sl[b >> 6] = loss_b; sc[b >> 6] = corr; }
    __syncthreads();
    if (b == 0) {
        out[0] = (sl[0] + sl[1]) / (float)BN;
        out[1] = sc[0] + sc[1];
    }
}

extern "C" void kernel_launch(void* const* d_in, const int* in_sizes, int n_in,
                              void* d_out, int out_size, void* d_ws, size_t ws_size,
                              hipStream_t stream) {
    const float* x   = (const float*)d_in[0];
    const int*   y   = (const int*)  d_in[1];
    const float* aW  = (const float*)d_in[2];
    const float* ab  = (const float*)d_in[3];
    const float* W1  = (const float*)d_in[4];
    const float* b1  = (const float*)d_in[5];
    const float* W2  = (const float*)d_in[6];
    const float* b2  = (const float*)d_in[7];
    const float* W3  = (const float*)d_in[8];
    const float* b3  = (const float*)d_in[9];
    const float* roW = (const float*)d_in[10];
    const float* rob = (const float*)d_in[11];
    float* out = (float*)d_out;
    float* ws  = (float*)d_ws;

    const size_t ZSZ = (size_t)BN * HCn * NPX;    // 4.19M floats
    const size_t HSZ = (size_t)BN * HHCn * NPX;   // 16.78M floats
    float* z      = ws;
    float* kb     = z + ZSZ;
    float* accb   = kb + ZSZ;
    float* h1     = accb + ZSZ;
    float* h2     = h1 + HSZ;
    float* logits = h2 + HSZ;

    k_aug<<<BN, 256, 0, stream>>>(x, aW, ab, z);

    for (int p = 0; p < PN; p++) {
        const float t0 = (float)p;
        const float alphas[4] = {0.f, 0.5f, 0.5f, 1.0f};
        const float ts[4]     = {t0, t0 + 0.5f, t0 + 0.5f, t0 + 1.0f};
        const int   idxs[4]   = {p, p, p, (p + 1 < PN ? p + 1 : PN - 1)};
        const int   modes[4]  = {0, 1, 1, 2};
        for (int e = 0; e < 4; e++) {
            const int idx = idxs[e];
            k_conv1<<<dim3(8, BN), 256, 0, stream>>>(
                z, kb, alphas[e],
                W1 + (size_t)idx * HHCn * 33, b1 + (size_t)idx * HHCn, ts[e], h1);
            k_conv3<<<dim3(4, BN), 256, 0, stream>>>(
                h1, W2 + (size_t)idx * HHCn * HHCn * 9, b2 + (size_t)idx * HHCn, h2);
            k_convw3<<<dim3(2, BN), 256, 0, stream>>>(
                h2, W3 + (size_t)idx * HCn * HHCn, b3 + (size_t)idx * HCn,
                kb, accb, z, modes[e]);
        }
    }

    k_logits<<<BN, 256, 0, stream>>>(z, roW, rob, logits);
    k_loss<<<1, 128, 0, stream>>>(logits, y, out);
}

// Round 3
// 4680.165 us; speedup vs baseline: 3.2089x; 3.2089x over previous
//
#include <hip/hip_runtime.h>
#include <math.h>

// Problem constants
#define BN   128      // batch
#define CIN  3
#define HCn  32       // hidden channels (ODE state)
#define HHCn 128      // inner hidden channels
#define NPX  1024     // 32*32
#define PN   4        // pieces
#define NCLS 10

typedef short bf16x8 __attribute__((ext_vector_type(8)));
typedef float f32x4  __attribute__((ext_vector_type(4)));

__device__ __forceinline__ float softplus_f(float x) {
    return fmaxf(x, 0.f) + log1pf(expf(-fabsf(x)));
}
__device__ __forceinline__ unsigned int f2bf(float f) {   // RNE fp32->bf16 bits
    unsigned int u = __float_as_uint(f);
    return (u + 0x7fffu + ((u >> 16) & 1u)) >> 16;
}
__device__ __forceinline__ float bf2f(unsigned int h) {
    return __uint_as_float(h << 16);
}

// ---------------- augment: z = x * aug_W^T + aug_b  (1x1 conv 3->32) ----------------
__global__ __launch_bounds__(256) void k_aug(
    const float* __restrict__ x, const float* __restrict__ aW,
    const float* __restrict__ ab, float* __restrict__ z)
{
    const int b = blockIdx.x, tid = threadIdx.x;
    const size_t xb = (size_t)b * CIN * NPX;
    const size_t zb = (size_t)b * HCn * NPX;
    float xv[CIN][4];
#pragma unroll
    for (int c = 0; c < CIN; c++)
#pragma unroll
        for (int j = 0; j < 4; j++)
            xv[c][j] = x[xb + c * NPX + tid + 256 * j];
    for (int o = 0; o < HCn; o++) {
        float w0 = aW[o * 3], w1 = aW[o * 3 + 1], w2 = aW[o * 3 + 2], bb = ab[o];
#pragma unroll
        for (int j = 0; j < 4; j++) {
            float v = fmaf(w0, xv[0][j], fmaf(w1, xv[1][j], fmaf(w2, xv[2][j], bb)));
            z[zb + (size_t)o * NPX + tid + 256 * j] = v;
        }
    }
}

// ---------------- conv1: h1 = softplus(W1 * [t ; (z + alpha*k)] + b1) ----------------
__global__ __launch_bounds__(256) void k_conv1(
    const float* __restrict__ z, const float* __restrict__ kb, float alpha,
    const float* __restrict__ W1p, const float* __restrict__ b1p, float t,
    float* __restrict__ h1)
{
    const int b = blockIdx.y, ocg = blockIdx.x, tid = threadIdx.x;
    const int oc0 = ocg * 16;
    float acc[16][4];
#pragma unroll
    for (int o = 0; o < 16; o++) {
        float eb = b1p[oc0 + o] + t * W1p[(oc0 + o) * 33];   // t folded into bias
#pragma unroll
        for (int j = 0; j < 4; j++) acc[o][j] = eb;
    }
    const size_t zb = (size_t)b * HCn * NPX;
    for (int ic = 0; ic < HCn; ic++) {
        float inv[4];
#pragma unroll
        for (int j = 0; j < 4; j++) {
            size_t idx = zb + (size_t)ic * NPX + tid + 256 * j;
            float v = z[idx];
            if (alpha != 0.f) v = fmaf(alpha, kb[idx], v);
            inv[j] = v;
        }
#pragma unroll
        for (int o = 0; o < 16; o++) {
            float w = W1p[(oc0 + o) * 33 + 1 + ic];
#pragma unroll
            for (int j = 0; j < 4; j++) acc[o][j] = fmaf(w, inv[j], acc[o][j]);
        }
    }
    const size_t hb = (size_t)b * HHCn * NPX;
#pragma unroll
    for (int o = 0; o < 16; o++)
#pragma unroll
        for (int j = 0; j < 4; j++)
            h1[hb + (size_t)(oc0 + o) * NPX + tid + 256 * j] = softplus_f(acc[o][j]);
}

// ---------------- pack W2 (all pieces) into MFMA A-fragment order, bf16 hi/lo -------
// dst layout: [p][sh][kc][ocg][lane][j] ; oc = ocg*16+(lane&15), ic = kc*32+(lane>>4)*8+j
__global__ __launch_bounds__(256) void k_packW2(
    const float* __restrict__ W2, unsigned short* __restrict__ whi,
    unsigned short* __restrict__ wlo)
{
    int t = blockIdx.x * 256 + threadIdx.x;          // < 4*9*4*8*64*8 = 589824
    int j    = t & 7;
    int lane = (t >> 3) & 63;
    int ocg  = (t >> 9) & 7;
    int kc   = (t >> 12) & 3;
    int p9s  = t >> 14;                              // p*9 + sh
    int sh = p9s % 9, p = p9s / 9;
    int dy = sh / 3, dx = sh % 3;
    int oc = ocg * 16 + (lane & 15);
    int ic = kc * 32 + (lane >> 4) * 8 + j;
    float v = W2[((((size_t)p * HHCn + oc) * HHCn + ic) * 3 + dy) * 3 + dx];
    unsigned int hi = f2bf(v);
    unsigned int lo = f2bf(v - bf2f(hi));
    whi[t] = (unsigned short)hi;
    wlo[t] = (unsigned short)lo;
}

// ---------------- conv3x3 via MFMA (bf16 hi/lo split, implicit GEMM) ----------------
// grid (4 strips, B), 512 thr (8 waves). Block: 128 oc x 256 px (8 rows x 32 cols).
// Wave: 32 oc x 128 px. K: 4 chunks of 32 ic, 9 shifts; X staged in LDS per chunk.
#define XPITCH 40    // ic pitch in LDS (ushorts), 80B -> 16B aligned, 8-way wr conflict
__global__ __launch_bounds__(512, 4) void k_conv3_mfma(
    const float* __restrict__ h1, const unsigned short* __restrict__ whi,
    const unsigned short* __restrict__ wlo, const float* __restrict__ b2p,
    int piece, float* __restrict__ h2)
{
    const int strip = blockIdx.x;            // 0..3 (8 output rows each)
    const int b     = blockIdx.y;
    const int tid = threadIdx.x, lane = tid & 63, wid = tid >> 6;
    const int wocg = (wid & 3) * 2;          // base ocg (16-oc units): 0,2,4,6
    const int wph  = (wid >> 2) * 128;       // px half: 0 or 128
    __shared__ __align__(16) unsigned short xhi[340 * XPITCH];
    __shared__ __align__(16) unsigned short xlo[340 * XPITCH];

    const int kl8  = (lane >> 4) * 8;        // k sub-offset within fragment
    const int ln15 = lane & 15;
    int boff[8];                             // LDS base (ushort units) per n-frag
#pragma unroll
    for (int f = 0; f < 8; f++) {
        int pxl  = wph + f * 16 + ln15;
        int ppad = (pxl >> 5) * 34 + (pxl & 31);
        boff[f] = ppad * XPITCH + kl8;
    }

    f32x4 acc[2][8];
#pragma unroll
    for (int o = 0; o < 2; o++)
#pragma unroll
        for (int f = 0; f < 8; f++) acc[o][f] = (f32x4)(0.f);

    const int strip0 = strip * 8;
    const size_t hb = (size_t)b * HHCn * NPX;
    unsigned int* xh32 = (unsigned int*)xhi;
    unsigned int* xl32 = (unsigned int*)xlo;

    for (int kc = 0; kc < 4; kc++) {
        __syncthreads();
        // stage 32 ic x (10x34) px, hi/lo, 2 ic packed per 32-bit LDS write
        for (int i = tid; i < 340 * 16; i += 512) {
            int icp = i / 340, ppad = i - icp * 340;
            int prow = ppad / 34, pcol = ppad - prow * 34;
            int gy = strip0 + prow - 1, gx = pcol - 1;
            bool valid = (gy >= 0) & (gy < 32) & (gx >= 0) & (gx < 32);
            float f0 = 0.f, f1 = 0.f;
            if (valid) {
                const float* s = h1 + hb + (size_t)(kc * 32 + icp * 2) * NPX + gy * 32 + gx;
                f0 = s[0]; f1 = s[NPX];
            }
            unsigned int h0 = f2bf(f0), h1v = f2bf(f1);
            unsigned int l0 = f2bf(f0 - bf2f(h0)), l1 = f2bf(f1 - bf2f(h1v));
            xh32[ppad * (XPITCH / 2) + icp] = h0 | (h1v << 16);
            xl32[ppad * (XPITCH / 2) + icp] = l0 | (l1 << 16);
        }
        __syncthreads();

#pragma unroll
        for (int sh = 0; sh < 9; sh++) {
            const int dy = sh / 3, dx = sh % 3;
            const size_t wbase = ((((size_t)(piece * 9 + sh) * 4 + kc) * 8 + wocg) * 64 + lane) * 8;
            bf16x8 ah0 = *(const bf16x8*)(whi + wbase);
            bf16x8 al0 = *(const bf16x8*)(wlo + wbase);
            bf16x8 ah1 = *(const bf16x8*)(whi + wbase + 512);
            bf16x8 al1 = *(const bf16x8*)(wlo + wbase + 512);
            const int soff = (dy * 34 + dx) * XPITCH;
#pragma unroll
            for (int f = 0; f < 8; f++) {
                bf16x8 bh = *(const bf16x8*)(xhi + boff[f] + soff);
                bf16x8 bl = *(const bf16x8*)(xlo + boff[f] + soff);
                acc[0][f] = __builtin_amdgcn_mfma_f32_16x16x32_bf16(ah0, bh, acc[0][f], 0, 0, 0);
                acc[0][f] = __builtin_amdgcn_mfma_f32_16x16x32_bf16(ah0, bl, acc[0][f], 0, 0, 0);
                acc[0][f] = __builtin_amdgcn_mfma_f32_16x16x32_bf16(al0, bh, acc[0][f], 0, 0, 0);
                acc[1][f] = __builtin_amdgcn_mfma_f32_16x16x32_bf16(ah1, bh, acc[1][f], 0, 0, 0);
                acc[1][f] = __builtin_amdgcn_mfma_f32_16x16x32_bf16(ah1, bl, acc[1][f], 0, 0, 0);
                acc[1][f] = __builtin_amdgcn_mfma_f32_16x16x32_bf16(al1, bh, acc[1][f], 0, 0, 0);
            }
        }
    }

    // epilogue: bias + softplus, C frag mapping: row=(lane>>4)*4+r, col=lane&15
    const size_t ob = (size_t)b * HHCn * NPX + strip * 256;
#pragma unroll
    for (int o2 = 0; o2 < 2; o2++) {
        int ocb = (wocg + o2) * 16 + (kl8 >> 1);   // (lane>>4)*4
#pragma unroll
        for (int r = 0; r < 4; r++) {
            int oc = ocb + r;
            float bb = b2p[oc];
#pragma unroll
            for (int f = 0; f < 8; f++) {
                int px = wph + f * 16 + ln15;
                h2[ob + (size_t)oc * NPX + px] = softplus_f(acc[o2][f][r] + bb);
            }
        }
    }
}

// ---------------- convw3: k = tanh(W3*h2 + b3), fused RK4 accumulation ----------------
__global__ __launch_bounds__(256) void k_convw3(
    const float* __restrict__ h2, const float* __restrict__ W3p,
    const float* __restrict__ b3p, float* __restrict__ kb,
    float* __restrict__ accb, float* __restrict__ zb_, int mode)
{
    const int b = blockIdx.y, ocg = blockIdx.x, tid = threadIdx.x;
    const int oc0 = ocg * 16;
    float acc[16][4];
#pragma unroll
    for (int o = 0; o < 16; o++) {
        float eb = b3p[oc0 + o];
#pragma unroll
        for (int j = 0; j < 4; j++) acc[o][j] = eb;
    }
    const size_t hb = (size_t)b * HHCn * NPX;
    for (int ic = 0; ic < HHCn; ic++) {
        float inv[4];
#pragma unroll
        for (int j = 0; j < 4; j++)
            inv[j] = h2[hb + (size_t)ic * NPX + tid + 256 * j];
#pragma unroll
        for (int o = 0; o < 16; o++) {
            float w = W3p[(oc0 + o) * HHCn + ic];
#pragma unroll
            for (int j = 0; j < 4; j++) acc[o][j] = fmaf(w, inv[j], acc[o][j]);
        }
    }
    const size_t ob = (size_t)b * HCn * NPX;
#pragma unroll
    for (int o = 0; o < 16; o++)
#pragma unroll
        for (int j = 0; j < 4; j++) {
            float v = tanhf(acc[o][j]);
            size_t i = ob + (size_t)(oc0 + o) * NPX + tid + 256 * j;
            if (mode == 0)      { kb[i] = v; accb[i] = v; }
            else if (mode == 1) { kb[i] = v; accb[i] += 2.f * v; }
            else                { zb_[i] += (accb[i] + v) * (1.f / 6.f); }
        }
}

// ---------------- readout ----------------
__global__ __launch_bounds__(256) void k_logits(
    const float* __restrict__ z, const float* __restrict__ roW,
    const float* __restrict__ rob, float* __restrict__ logits)
{
    const int b = blockIdx.x, tid = threadIdx.x;
    float p[NCLS];
#pragma unroll
    for (int c = 0; c < NCLS; c++) p[c] = 0.f;
    const float* zp = z + (size_t)b * 32768;
    for (int i = tid; i < 32768; i += 256) {
        float zv = zp[i];
#pragma unroll
        for (int c = 0; c < NCLS; c++) p[c] = fmaf(zv, roW[(size_t)c * 32768 + i], p[c]);
    }
#pragma unroll
    for (int c = 0; c < NCLS; c++)
        for (int off = 32; off > 0; off >>= 1) p[c] += __shfl_down(p[c], off, 64);
    __shared__ float red[4][NCLS];
    int wid = tid >> 6, lane = tid & 63;
    if (lane == 0)
#pragma unroll
        for (int c = 0; c < NCLS; c++) red[wid][c] = p[c];
    __syncthreads();
    if (tid < NCLS) {
        float s = red[0][tid] + red[1][tid] + red[2][tid] + red[3][tid] + rob[tid];
        logits[b * NCLS + tid] = s;
    }
}

// ---------------- loss + accuracy ----------------
__global__ __launch_bounds__(128) void k_loss(
    const float* __restrict__ logits, const int* __restrict__ y,
    float* __restrict__ out)
{
    const int b = threadIdx.x;   // 0..127
    float l[NCLS];
#pragma unroll
    for (int c = 0; c < NCLS; c++) l[c] = logits[b * NCLS + c];
    float m = l[0]; int am = 0;
#pragma unroll
    for (int c = 1; c < NCLS; c++) if (l[c] > m) { m = l[c]; am = c; }
    float s = 0.f;
#pragma unroll
    for (int c = 0; c < NCLS; c++) s += expf(l[c] - m);
    float lse = m + logf(s);
    int yy = y[b];
    float loss_b = lse - l[yy];
    float corr = (am == yy) ? 1.f : 0.f;
    for (int off = 32; off > 0; off >>= 1) {
        loss_b += __shfl_down(loss_b, off, 64);
        corr   += __shfl_down(corr,   off, 64);
    }
    __shared__ float sl[2], sc[2];
    if ((b & 63) == 0) { sl[b >> 6] = loss_b; sc[b >> 6] = corr; }
    __syncthreads();
    if (b == 0) {
        out[0] = (sl[0] + sl[1]) / (float)BN;
        out[1] = sc[0] + sc[1];
    }
}

extern "C" void kernel_launch(void* const* d_in, const int* in_sizes, int n_in,
                              void* d_out, int out_size, void* d_ws, size_t ws_size,
                              hipStream_t stream) {
    const float* x   = (const float*)d_in[0];
    const int*   y   = (const int*)  d_in[1];
    const float* aW  = (const float*)d_in[2];
    const float* ab  = (const float*)d_in[3];
    const float* W1  = (const float*)d_in[4];
    const float* b1  = (const float*)d_in[5];
    const float* W2  = (const float*)d_in[6];
    const float* b2  = (const float*)d_in[7];
    const float* W3  = (const float*)d_in[8];
    const float* b3  = (const float*)d_in[9];
    const float* roW = (const float*)d_in[10];
    const float* rob = (const float*)d_in[11];
    float* out = (float*)d_out;
    float* ws  = (float*)d_ws;

    const size_t ZSZ = (size_t)BN * HCn * NPX;    // 4.19M floats
    const size_t HSZ = (size_t)BN * HHCn * NPX;   // 16.78M floats
    float* z      = ws;
    float* kb     = z + ZSZ;
    float* accb   = kb + ZSZ;
    float* h1     = accb + ZSZ;
    float* h2     = h1 + HSZ;
    float* logits = h2 + HSZ;
    unsigned short* whi = (unsigned short*)(logits + 4096);
    unsigned short* wlo = whi + 589824;           // 4*9*4*8*64*8

    k_packW2<<<589824 / 256, 256, 0, stream>>>(W2, whi, wlo);
    k_aug<<<BN, 256, 0, stream>>>(x, aW, ab, z);

    for (int p = 0; p < PN; p++) {
        const float t0 = (float)p;
        const float alphas[4] = {0.f, 0.5f, 0.5f, 1.0f};
        const float ts[4]     = {t0, t0 + 0.5f, t0 + 0.5f, t0 + 1.0f};
        const int   idxs[4]   = {p, p, p, (p + 1 < PN ? p + 1 : PN - 1)};
        const int   modes[4]  = {0, 1, 1, 2};
        for (int e = 0; e < 4; e++) {
            const int idx = idxs[e];
            k_conv1<<<dim3(8, BN), 256, 0, stream>>>(
                z, kb, alphas[e],
                W1 + (size_t)idx * HHCn * 33, b1 + (size_t)idx * HHCn, ts[e], h1);
            k_conv3_mfma<<<dim3(4, BN), 512, 0, stream>>>(
                h1, whi, wlo, b2 + (size_t)idx * HHCn, idx, h2);
            k_convw3<<<dim3(2, BN), 256, 0, stream>>>(
                h2, W3 + (size_t)idx * HCn * HHCn, b3 + (size_t)idx * HCn,
                kb, accb, z, modes[e]);
        }
    }

    k_logits<<<BN, 256, 0, stream>>>(z, roW, rob, logits);
    k_loss<<<1, 128, 0, stream>>>(logits, y, out);
}

// Round 4
// 4573.875 us; speedup vs baseline: 3.2834x; 1.0232x over previous
//
#include <hip/hip_runtime.h>
#include <math.h>

// Problem constants
#define BN   128      // batch
#define CIN  3
#define HCn  32       // hidden channels (ODE state)
#define HHCn 128      // inner hidden channels
#define NPX  1024     // 32*32
#define PN   4        // pieces
#define NCLS 10

typedef short bf16x8 __attribute__((ext_vector_type(8)));
typedef float f32x4  __attribute__((ext_vector_type(4)));

__device__ __forceinline__ float softplus_f(float x) {
    return fmaxf(x, 0.f) + log1pf(expf(-fabsf(x)));
}
__device__ __forceinline__ unsigned int f2bf(float f) {   // RNE fp32->bf16 bits
    unsigned int u = __float_as_uint(f);
    return (u + 0x7fffu + ((u >> 16) & 1u)) >> 16;
}
__device__ __forceinline__ float bf2f(unsigned int h) {
    return __uint_as_float(h << 16);
}

// ---------------- augment: z = x * aug_W^T + aug_b  (1x1 conv 3->32) ----------------
__global__ __launch_bounds__(256) void k_aug(
    const float* __restrict__ x, const float* __restrict__ aW,
    const float* __restrict__ ab, float* __restrict__ z)
{
    const int b = blockIdx.x, tid = threadIdx.x;
    const size_t xb = (size_t)b * CIN * NPX;
    const size_t zb = (size_t)b * HCn * NPX;
    float xv[CIN][4];
#pragma unroll
    for (int c = 0; c < CIN; c++)
#pragma unroll
        for (int j = 0; j < 4; j++)
            xv[c][j] = x[xb + c * NPX + tid + 256 * j];
    for (int o = 0; o < HCn; o++) {
        float w0 = aW[o * 3], w1 = aW[o * 3 + 1], w2 = aW[o * 3 + 2], bb = ab[o];
#pragma unroll
        for (int j = 0; j < 4; j++) {
            float v = fmaf(w0, xv[0][j], fmaf(w1, xv[1][j], fmaf(w2, xv[2][j], bb)));
            z[zb + (size_t)o * NPX + tid + 256 * j] = v;
        }
    }
}

// ---------------- conv1: h1pk = pack_bf16_hilo(softplus(W1*[t; z+alpha*k] + b1)) ----
// grid (8, B), 256 thr; 16 oc x 4 consecutive px per thread.
// Output layout: uint2 h1pk[b][icp=oc/2][px] ; .x = hi(oc)|hi(oc+1)<<16, .y = lo pair.
__global__ __launch_bounds__(256) void k_conv1(
    const float* __restrict__ z, const float* __restrict__ kb, float alpha,
    const float* __restrict__ W1p, const float* __restrict__ b1p, float t,
    uint2* __restrict__ h1pk)
{
    const int b = blockIdx.y, ocg = blockIdx.x, tid = threadIdx.x;
    const int oc0 = ocg * 16, px0 = tid * 4;
    float acc[16][4];
#pragma unroll
    for (int o = 0; o < 16; o++) {
        float eb = b1p[oc0 + o] + t * W1p[(oc0 + o) * 33];   // t folded into bias
#pragma unroll
        for (int j = 0; j < 4; j++) acc[o][j] = eb;
    }
    const size_t zb = (size_t)b * HCn * NPX;
    for (int ic = 0; ic < HCn; ic++) {
        f32x4 zv = *(const f32x4*)(z + zb + (size_t)ic * NPX + px0);
        if (alpha != 0.f) {
            f32x4 kv = *(const f32x4*)(kb + zb + (size_t)ic * NPX + px0);
#pragma unroll
            for (int j = 0; j < 4; j++) zv[j] = fmaf(alpha, kv[j], zv[j]);
        }
#pragma unroll
        for (int o = 0; o < 16; o++) {
            float w = W1p[(oc0 + o) * 33 + 1 + ic];
#pragma unroll
            for (int j = 0; j < 4; j++) acc[o][j] = fmaf(w, zv[j], acc[o][j]);
        }
    }
    const size_t ob = (size_t)b * 64 * NPX;   // 64 icp per batch
#pragma unroll
    for (int r = 0; r < 8; r++) {
        const size_t rowb = ob + (size_t)(ocg * 8 + r) * NPX + px0;
#pragma unroll
        for (int j = 0; j < 4; j++) {
            float v0 = softplus_f(acc[2 * r][j]);
            float v1 = softplus_f(acc[2 * r + 1][j]);
            unsigned int h0 = f2bf(v0), h1v = f2bf(v1);
            unsigned int l0 = f2bf(v0 - bf2f(h0)), l1 = f2bf(v1 - bf2f(h1v));
            uint2 pk; pk.x = h0 | (h1v << 16); pk.y = l0 | (l1 << 16);
            h1pk[rowb + j] = pk;
        }
    }
}

// ---------------- pack W2 (all pieces) into MFMA A-fragment order, bf16 hi/lo -------
// dst layout: [p][sh][kc][ocg][lane][j] ; oc = ocg*16+(lane&15), ic = kc*32+(lane>>4)*8+j
__global__ __launch_bounds__(256) void k_packW2(
    const float* __restrict__ W2, unsigned short* __restrict__ whi,
    unsigned short* __restrict__ wlo)
{
    int t = blockIdx.x * 256 + threadIdx.x;          // < 4*9*4*8*64*8 = 589824
    int j    = t & 7;
    int lane = (t >> 3) & 63;
    int ocg  = (t >> 9) & 7;
    int kc   = (t >> 12) & 3;
    int p9s  = t >> 14;                              // p*9 + sh
    int sh = p9s % 9, p = p9s / 9;
    int dy = sh / 3, dx = sh % 3;
    int oc = ocg * 16 + (lane & 15);
    int ic = kc * 32 + (lane >> 4) * 8 + j;
    float v = W2[((((size_t)p * HHCn + oc) * HHCn + ic) * 3 + dy) * 3 + dx];
    unsigned int hi = f2bf(v);
    unsigned int lo = f2bf(v - bf2f(hi));
    whi[t] = (unsigned short)hi;
    wlo[t] = (unsigned short)lo;
}

// ---------------- conv3x3 via MFMA (bf16 hi/lo split, implicit GEMM) ----------------
// grid (4 strips, B), 512 thr (8 waves). Block: 128 oc x 256 px (8 rows x 32 cols).
// Staging: wave w stages icp2=w (4 ic) via uint2 global loads + b64 LDS writes.
#define XPITCH 40    // row pitch in ushorts (80B, 16B-aligned for b128 frag reads)
__global__ __launch_bounds__(512, 4) void k_conv3_mfma(
    const uint2* __restrict__ h1pk, const unsigned short* __restrict__ whi,
    const unsigned short* __restrict__ wlo, const float* __restrict__ b2p,
    int piece, float* __restrict__ h2)
{
    const int strip = blockIdx.x;            // 0..3 (8 output rows each)
    const int b     = blockIdx.y;
    const int tid = threadIdx.x, lane = tid & 63, wid = tid >> 6;
    const int wocg = (wid & 3) * 2;          // base ocg (16-oc units): 0,2,4,6
    const int wph  = (wid >> 2) * 128;       // px half: 0 or 128
    __shared__ __align__(16) unsigned short xhi[340 * XPITCH];
    __shared__ __align__(16) unsigned short xlo[340 * XPITCH];
    unsigned int* xh32 = (unsigned int*)xhi;
    unsigned int* xl32 = (unsigned int*)xlo;

    const int kl8  = (lane >> 4) * 8;        // k sub-offset within fragment
    const int ln15 = lane & 15;
    int boff[8];                             // LDS base (ushort units) per n-frag
#pragma unroll
    for (int f = 0; f < 8; f++) {
        int pxl  = wph + f * 16 + ln15;
        int ppad = (pxl >> 5) * 34 + (pxl & 31);
        boff[f] = ppad * XPITCH + kl8;
    }

    // hoisted staging map (5.3125 iters of 64 lanes over 340 ppad)
    int gsrc[6]; bool ok[6];
    const int strip0 = strip * 8;
#pragma unroll
    for (int it = 0; it < 6; it++) {
        int ppad = it * 64 + lane;
        int prow = ppad / 34, pcol = ppad - prow * 34;
        int gy = strip0 + prow - 1, gx = pcol - 1;
        ok[it] = (ppad < 340) & (gy >= 0) & (gy < 32) & (gx >= 0) & (gx < 32);
        gsrc[it] = gy * 32 + gx;
    }

    f32x4 acc[2][8];
#pragma unroll
    for (int o = 0; o < 2; o++)
#pragma unroll
        for (int f = 0; f < 8; f++) acc[o][f] = (f32x4)(0.f);

    const size_t hb = (size_t)b * 64 * NPX;  // h1pk batch base (uint2 units)

    for (int kc = 0; kc < 4; kc++) {
        __syncthreads();
        // wave w stages its 2 icp rows (4 ic): uint2 loads, b64 LDS writes
        const size_t srcA = hb + (size_t)(kc * 16 + 2 * wid) * NPX;
        const size_t srcB = srcA + NPX;
        const int wsl = 2 * wid;             // u32 slot within row
#pragma unroll
        for (int it = 0; it < 6; it++) {
            int ppad = it * 64 + lane;
            uint2 A = make_uint2(0u, 0u), Bv = make_uint2(0u, 0u);
            if (ok[it]) { A = h1pk[srcA + gsrc[it]]; Bv = h1pk[srcB + gsrc[it]]; }
            if (ppad < 340) {
                *(uint2*)(xh32 + ppad * (XPITCH / 2) + wsl) = make_uint2(A.x, Bv.x);
                *(uint2*)(xl32 + ppad * (XPITCH / 2) + wsl) = make_uint2(A.y, Bv.y);
            }
        }
        __syncthreads();

#pragma unroll
        for (int sh = 0; sh < 9; sh++) {
            const int dy = sh / 3, dx = sh % 3;
            const size_t wbase = ((((size_t)(piece * 9 + sh) * 4 + kc) * 8 + wocg) * 64 + lane) * 8;
            bf16x8 ah0 = *(const bf16x8*)(whi + wbase);
            bf16x8 al0 = *(const bf16x8*)(wlo + wbase);
            bf16x8 ah1 = *(const bf16x8*)(whi + wbase + 512);
            bf16x8 al1 = *(const bf16x8*)(wlo + wbase + 512);
            const int soff = (dy * 34 + dx) * XPITCH;
#pragma unroll
            for (int f = 0; f < 8; f++) {
                bf16x8 bh = *(const bf16x8*)(xhi + boff[f] + soff);
                bf16x8 bl = *(const bf16x8*)(xlo + boff[f] + soff);
                acc[0][f] = __builtin_amdgcn_mfma_f32_16x16x32_bf16(ah0, bh, acc[0][f], 0, 0, 0);
                acc[0][f] = __builtin_amdgcn_mfma_f32_16x16x32_bf16(ah0, bl, acc[0][f], 0, 0, 0);
                acc[0][f] = __builtin_amdgcn_mfma_f32_16x16x32_bf16(al0, bh, acc[0][f], 0, 0, 0);
                acc[1][f] = __builtin_amdgcn_mfma_f32_16x16x32_bf16(ah1, bh, acc[1][f], 0, 0, 0);
                acc[1][f] = __builtin_amdgcn_mfma_f32_16x16x32_bf16(ah1, bl, acc[1][f], 0, 0, 0);
                acc[1][f] = __builtin_amdgcn_mfma_f32_16x16x32_bf16(al1, bh, acc[1][f], 0, 0, 0);
            }
        }
    }

    // epilogue: bias + softplus, C frag mapping: row(oc)=(lane>>4)*4+r, col(px)=lane&15
    const size_t ob = (size_t)b * HHCn * NPX + strip * 256;
#pragma unroll
    for (int o2 = 0; o2 < 2; o2++) {
        int ocb = (wocg + o2) * 16 + (kl8 >> 1);   // (lane>>4)*4
#pragma unroll
        for (int r = 0; r < 4; r++) {
            int oc = ocb + r;
            float bb = b2p[oc];
#pragma unroll
            for (int f = 0; f < 8; f++) {
                int px = wph + f * 16 + ln15;
                h2[ob + (size_t)oc * NPX + px] = softplus_f(acc[o2][f][r] + bb);
            }
        }
    }
}

// ---------------- convw3: k = tanh(W3*h2 + b3), fused RK4 accumulation ----------------
// mode 0: k=v, acc=v ; mode 1: k=v, acc+=2v ; mode 2: z += (acc+v)/6
// grid (8, B): ocg = bx&1 (16 oc), pxg = bx>>1 (256-px window); thread = 1 px.
__global__ __launch_bounds__(256) void k_convw3(
    const float* __restrict__ h2, const float* __restrict__ W3p,
    const float* __restrict__ b3p, float* __restrict__ kb,
    float* __restrict__ accb, float* __restrict__ zb_, int mode)
{
    const int b = blockIdx.y, bx = blockIdx.x, tid = threadIdx.x;
    const int oc0 = (bx & 1) * 16;
    const int px = (bx >> 1) * 256 + tid;
    float acc[16];
#pragma unroll
    for (int o = 0; o < 16; o++) acc[o] = b3p[oc0 + o];
    const size_t hb = (size_t)b * HHCn * NPX;
    for (int ic = 0; ic < HHCn; ic++) {
        float inv = h2[hb + (size_t)ic * NPX + px];
#pragma unroll
        for (int o = 0; o < 16; o++)
            acc[o] = fmaf(W3p[(oc0 + o) * HHCn + ic], inv, acc[o]);
    }
    const size_t ob = (size_t)b * HCn * NPX;
#pragma unroll
    for (int o = 0; o < 16; o++) {
        float v = tanhf(acc[o]);
        size_t i = ob + (size_t)(oc0 + o) * NPX + px;
        if (mode == 0)      { kb[i] = v; accb[i] = v; }
        else if (mode == 1) { kb[i] = v; accb[i] += 2.f * v; }
        else                { zb_[i] += (accb[i] + v) * (1.f / 6.f); }
    }
}

// ---------------- readout ----------------
__global__ __launch_bounds__(256) void k_logits(
    const float* __restrict__ z, const float* __restrict__ roW,
    const float* __restrict__ rob, float* __restrict__ logits)
{
    const int b = blockIdx.x, tid = threadIdx.x;
    float p[NCLS];
#pragma unroll
    for (int c = 0; c < NCLS; c++) p[c] = 0.f;
    const float* zp = z + (size_t)b * 32768;
    for (int i = tid; i < 32768; i += 256) {
        float zv = zp[i];
#pragma unroll
        for (int c = 0; c < NCLS; c++) p[c] = fmaf(zv, roW[(size_t)c * 32768 + i], p[c]);
    }
#pragma unroll
    for (int c = 0; c < NCLS; c++)
        for (int off = 32; off > 0; off >>= 1) p[c] += __shfl_down(p[c], off, 64);
    __shared__ float red[4][NCLS];
    int wid = tid >> 6, lane = tid & 63;
    if (lane == 0)
#pragma unroll
        for (int c = 0; c < NCLS; c++) red[wid][c] = p[c];
    __syncthreads();
    if (tid < NCLS) {
        float s = red[0][tid] + red[1][tid] + red[2][tid] + red[3][tid] + rob[tid];
        logits[b * NCLS + tid] = s;
    }
}

// ---------------- loss + accuracy ----------------
__global__ __launch_bounds__(128) void k_loss(
    const float* __restrict__ logits, const int* __restrict__ y,
    float* __restrict__ out)
{
    const int b = threadIdx.x;   // 0..127
    float l[NCLS];
#pragma unroll
    for (int c = 0; c < NCLS; c++) l[c] = logits[b * NCLS + c];
    float m = l[0]; int am = 0;
#pragma unroll
    for (int c = 1; c < NCLS; c++) if (l[c] > m) { m = l[c]; am = c; }
    float s = 0.f;
#pragma unroll
    for (int c = 0; c < NCLS; c++) s += expf(l[c] - m);
    float lse = m + logf(s);
    int yy = y[b];
    float loss_b = lse - l[yy];
    float corr = (am == yy) ? 1.f : 0.f;
    for (int off = 32; off > 0; off >>= 1) {
        loss_b += __shfl_down(loss_b, off, 64);
        corr   += __shfl_down(corr,   off, 64);
    }
    __shared__ float sl[2], sc[2];
    if ((b & 63) == 0) { sl[b >> 6] = loss_b; sc[b >> 6] = corr; }
    __syncthreads();
    if (b == 0) {
        out[0] = (sl[0] + sl[1]) / (float)BN;
        out[1] = sc[0] + sc[1];
    }
}

extern "C" void kernel_launch(void* const* d_in, const int* in_sizes, int n_in,
                              void* d_out, int out_size, void* d_ws, size_t ws_size,
                              hipStream_t stream) {
    const float* x   = (const float*)d_in[0];
    const int*   y   = (const int*)  d_in[1];
    const float* aW  = (const float*)d_in[2];
    const float* ab  = (const float*)d_in[3];
    const float* W1  = (const float*)d_in[4];
    const float* b1  = (const float*)d_in[5];
    const float* W2  = (const float*)d_in[6];
    const float* b2  = (const float*)d_in[7];
    const float* W3  = (const float*)d_in[8];
    const float* b3  = (const float*)d_in[9];
    const float* roW = (const float*)d_in[10];
    const float* rob = (const float*)d_in[11];
    float* out = (float*)d_out;
    float* ws  = (float*)d_ws;

    const size_t ZSZ = (size_t)BN * HCn * NPX;    // 4.19M floats
    const size_t HSZ = (size_t)BN * HHCn * NPX;   // 16.78M floats
    float* z      = ws;
    float* kb     = z + ZSZ;
    float* accb   = kb + ZSZ;
    uint2* h1pk   = (uint2*)(accb + ZSZ);         // BN*64*NPX uint2 = HSZ floats
    float* h2     = (float*)(accb + ZSZ) + HSZ;
    float* logits = h2 + HSZ;
    unsigned short* whi = (unsigned short*)(logits + 4096);
    unsigned short* wlo = whi + 589824;           // 4*9*4*8*64*8

    k_packW2<<<589824 / 256, 256, 0, stream>>>(W2, whi, wlo);
    k_aug<<<BN, 256, 0, stream>>>(x, aW, ab, z);

    for (int p = 0; p < PN; p++) {
        const float t0 = (float)p;
        const float alphas[4] = {0.f, 0.5f, 0.5f, 1.0f};
        const float ts[4]     = {t0, t0 + 0.5f, t0 + 0.5f, t0 + 1.0f};
        const int   idxs[4]   = {p, p, p, (p + 1 < PN ? p + 1 : PN - 1)};
        const int   modes[4]  = {0, 1, 1, 2};
        for (int e = 0; e < 4; e++) {
            const int idx = idxs[e];
            k_conv1<<<dim3(8, BN), 256, 0, stream>>>(
                z, kb, alphas[e],
                W1 + (size_t)idx * HHCn * 33, b1 + (size_t)idx * HHCn, ts[e], h1pk);
            k_conv3_mfma<<<dim3(4, BN), 512, 0, stream>>>(
                h1pk, whi, wlo, b2 + (size_t)idx * HHCn, idx, h2);
            k_convw3<<<dim3(8, BN), 256, 0, stream>>>(
                h2, W3 + (size_t)idx * HCn * HHCn, b3 + (size_t)idx * HCn,
                kb, accb, z, modes[e]);
        }
    }

    k_logits<<<BN, 256, 0, stream>>>(z, roW, rob, logits);
    k_loss<<<1, 128, 0, stream>>>(logits, y, out);
}

// Round 5
// 4171.775 us; speedup vs baseline: 3.5999x; 1.0964x over previous
//
#include <hip/hip_runtime.h>
#include <math.h>

// Problem constants
#define BN   128      // batch
#define CIN  3
#define HCn  32       // hidden channels (ODE state)
#define HHCn 128      // inner hidden channels
#define NPX  1024     // 32*32
#define PN   4        // pieces
#define NCLS 10

#define ZP    40      // zin LDS pitch (ushorts): 80B rows, 2-way banks
#define XP    40      // X (h1 chunk) LDS pitch
#define H2P   136     // h2 quarter pitch: 272B rows, 2-way banks

typedef short bf16x8 __attribute__((ext_vector_type(8)));
typedef float f32x4  __attribute__((ext_vector_type(4)));

__device__ __forceinline__ float softplus_f(float x) {
    return fmaxf(x, 0.f) + log1pf(expf(-fabsf(x)));
}
__device__ __forceinline__ unsigned int f2bf(float f) {   // RNE fp32->bf16 bits
    unsigned int u = __float_as_uint(f);
    return (u + 0x7fffu + ((u >> 16) & 1u)) >> 16;
}
__device__ __forceinline__ float bf2f(unsigned int h) {
    return __uint_as_float(h << 16);
}
__device__ __forceinline__ void pack2(float a, float b, unsigned int& hi, unsigned int& lo) {
    unsigned int ha = f2bf(a), hb = f2bf(b);
    unsigned int la = f2bf(a - bf2f(ha)), lb = f2bf(b - bf2f(hb));
    hi = ha | (hb << 16);
    lo = la | (lb << 16);
}

// ---------------- augment: z = x * aug_W^T + aug_b  (1x1 conv 3->32) ----------------
__global__ __launch_bounds__(256) void k_aug(
    const float* __restrict__ x, const float* __restrict__ aW,
    const float* __restrict__ ab, float* __restrict__ z)
{
    const int b = blockIdx.x, tid = threadIdx.x;
    const size_t xb = (size_t)b * CIN * NPX;
    const size_t zb = (size_t)b * HCn * NPX;
    float xv[CIN][4];
#pragma unroll
    for (int c = 0; c < CIN; c++)
#pragma unroll
        for (int j = 0; j < 4; j++)
            xv[c][j] = x[xb + c * NPX + tid + 256 * j];
    for (int o = 0; o < HCn; o++) {
        float w0 = aW[o * 3], w1 = aW[o * 3 + 1], w2 = aW[o * 3 + 2], bb = ab[o];
#pragma unroll
        for (int j = 0; j < 4; j++) {
            float v = fmaf(w0, xv[0][j], fmaf(w1, xv[1][j], fmaf(w2, xv[2][j], bb)));
            z[zb + (size_t)o * NPX + tid + 256 * j] = v;
        }
    }
}

// ---------------- pack W2 into MFMA A-frag order, bf16 hi/lo ----------------
// layout: [p][sh][kc][ocg][lane][j] ; oc=ocg*16+(lane&15), ic=kc*32+(lane>>4)*8+j
__global__ __launch_bounds__(256) void k_packW2(
    const float* __restrict__ W2, unsigned short* __restrict__ whi,
    unsigned short* __restrict__ wlo)
{
    int t = blockIdx.x * 256 + threadIdx.x;          // < 589824
    int j    = t & 7;
    int lane = (t >> 3) & 63;
    int ocg  = (t >> 9) & 7;
    int kc   = (t >> 12) & 3;
    int p9s  = t >> 14;                              // p*9 + sh
    int sh = p9s % 9, p = p9s / 9;
    int dy = sh / 3, dx = sh % 3;
    int oc = ocg * 16 + (lane & 15);
    int ic = kc * 32 + (lane >> 4) * 8 + j;
    float v = W2[((((size_t)p * HHCn + oc) * HHCn + ic) * 3 + dy) * 3 + dx];
    unsigned int hi = f2bf(v);
    whi[t] = (unsigned short)hi;
    wlo[t] = (unsigned short)f2bf(v - bf2f(hi));
}

// ---------------- pack W1 (skip t-col): [p][kc][m][lane][j] -----------------
__global__ __launch_bounds__(256) void k_packW1(
    const float* __restrict__ W1, unsigned short* __restrict__ whi,
    unsigned short* __restrict__ wlo)
{
    int t = blockIdx.x * 256 + threadIdx.x;          // < 16384
    int j = t & 7, lane = (t >> 3) & 63, m = (t >> 9) & 1, kc = (t >> 10) & 3, p = t >> 12;
    int oc = kc * 32 + m * 16 + (lane & 15);
    int ic = (lane >> 4) * 8 + j;
    float v = W1[((size_t)p * HHCn + oc) * 33 + 1 + ic];
    unsigned int hi = f2bf(v);
    whi[t] = (unsigned short)hi;
    wlo[t] = (unsigned short)f2bf(v - bf2f(hi));
}

// ---------------- pack W3: [p][m][kk][lane][j] ------------------------------
__global__ __launch_bounds__(256) void k_packW3(
    const float* __restrict__ W3, unsigned short* __restrict__ whi,
    unsigned short* __restrict__ wlo)
{
    int t = blockIdx.x * 256 + threadIdx.x;          // < 16384
    int j = t & 7, lane = (t >> 3) & 63, kk = (t >> 9) & 3, m = (t >> 11) & 1, p = t >> 12;
    int st = m * 16 + (lane & 15);
    int ic = kk * 32 + (lane >> 4) * 8 + j;
    float v = W3[((size_t)p * HCn + st) * HHCn + ic];
    unsigned int hi = f2bf(v);
    whi[t] = (unsigned short)hi;
    wlo[t] = (unsigned short)f2bf(v - bf2f(hi));
}

// ---------------- fused f-eval: conv1 -> conv3x3 -> convw3 + RK4 ------------
// grid (4 strips, BN), 512 thr (8 waves). All GEMMs via mfma_f32_16x16x32_bf16
// with hi/lo 3-split. h1/h2 never leave the block (LDS/registers).
__global__ __launch_bounds__(512, 2) void k_fused(
    const float* __restrict__ z_in, const float* __restrict__ kb_in, float alpha,
    const float* __restrict__ b1p, const float* __restrict__ W1t, float t,
    const unsigned short* __restrict__ w1h, const unsigned short* __restrict__ w1l,
    const unsigned short* __restrict__ w2h, const unsigned short* __restrict__ w2l,
    const float* __restrict__ b2p,
    const unsigned short* __restrict__ w3h, const unsigned short* __restrict__ w3l,
    const float* __restrict__ b3p,
    float* __restrict__ kb_out, float* __restrict__ accb, float* __restrict__ z_out,
    int mode)
{
    const int strip = blockIdx.x, b = blockIdx.y;
    const int tid = threadIdx.x, lane = tid & 63, wid = tid >> 6;
    const int ln15 = lane & 15, kl8 = (lane >> 4) * 8, kl4 = (lane >> 4) * 4;

    __shared__ __align__(16) unsigned short S[56320];   // 112.6 KB
    unsigned short* zinh = S;                            // 352*40
    unsigned short* zinl = S + 14080;
    unsigned short* xh   = S + 28160;
    unsigned short* xl   = S + 42240;
    unsigned short* h2qh = S;                            // alias zin (freed)
    unsigned short* h2ql = S + 8704;                     // 64*136

    const size_t zbB = (size_t)b * HCn * NPX;
    const int strip0 = strip * 8;

    // ---- phase 0: stage zin = bf16hl(z + alpha*k), 32ic x 340 padded px ----
    {
        const int ic0 = wid * 4;
#pragma unroll
        for (int it = 0; it < 6; it++) {
            int ppad = it * 64 + lane;
            int prow = ppad / 34, pcol = ppad - prow * 34;
            int gy = strip0 + prow - 1, gx = pcol - 1;
            bool okm = (ppad < 340) && (gy >= 0) && (gy < 32) && (gx >= 0) && (gx < 32);
            int gsrc = gy * 32 + gx;
            float v[4];
#pragma unroll
            for (int c = 0; c < 4; c++)
                v[c] = okm ? z_in[zbB + (size_t)(ic0 + c) * NPX + gsrc] : 0.f;
            if (alpha != 0.f) {
#pragma unroll
                for (int c = 0; c < 4; c++)
                    if (okm) v[c] = fmaf(alpha, kb_in[zbB + (size_t)(ic0 + c) * NPX + gsrc], v[c]);
            }
            unsigned int h01, l01, h23, l23;
            pack2(v[0], v[1], h01, l01);
            pack2(v[2], v[3], h23, l23);
            if (ppad < 340) {
                *(uint2*)(zinh + ppad * ZP + ic0) = make_uint2(h01, h23);
                *(uint2*)(zinl + ppad * ZP + ic0) = make_uint2(l01, l23);
            }
        }
    }
    __syncthreads();

    const int wocg = (wid & 3) * 2;          // conv3 role: oc pair base
    const int wph  = (wid >> 2) * 128;       // conv3 role: px half
    int boff[8];
#pragma unroll
    for (int f = 0; f < 8; f++) {
        int pxl = wph + f * 16 + ln15;
        boff[f] = ((pxl >> 5) * 34 + (pxl & 31)) * XP + kl8;
    }

    f32x4 acc[2][8];
#pragma unroll
    for (int o = 0; o < 2; o++)
#pragma unroll
        for (int f = 0; f < 8; f++) acc[o][f] = (f32x4)(0.f);

    // ---- main loop: per 32-ic chunk: conv1 MFMA -> X LDS -> conv3 MFMA ----
    for (int kc = 0; kc < 4; kc++) {
        // conv1: [32oc x 32K] x zin[32K x 352px]; wave handles n = wid*3..+2
        const unsigned short* w1hb = w1h + (size_t)kc * 1024 + lane * 8;
        const unsigned short* w1lb = w1l + (size_t)kc * 1024 + lane * 8;
        bf16x8 a1h0 = *(const bf16x8*)w1hb,          a1h1 = *(const bf16x8*)(w1hb + 512);
        bf16x8 a1l0 = *(const bf16x8*)w1lb,          a1l1 = *(const bf16x8*)(w1lb + 512);
        f32x4 c1[2][3];
#pragma unroll
        for (int m = 0; m < 2; m++)
#pragma unroll
            for (int ni = 0; ni < 3; ni++) c1[m][ni] = (f32x4)(0.f);
#pragma unroll
        for (int ni = 0; ni < 3; ni++) {
            int n = wid * 3 + ni;
            if (n < 22) {
                bf16x8 bh = *(const bf16x8*)(zinh + (n * 16 + ln15) * ZP + kl8);
                bf16x8 bl = *(const bf16x8*)(zinl + (n * 16 + ln15) * ZP + kl8);
                c1[0][ni] = __builtin_amdgcn_mfma_f32_16x16x32_bf16(a1h0, bh, c1[0][ni], 0, 0, 0);
                c1[0][ni] = __builtin_amdgcn_mfma_f32_16x16x32_bf16(a1h0, bl, c1[0][ni], 0, 0, 0);
                c1[0][ni] = __builtin_amdgcn_mfma_f32_16x16x32_bf16(a1l0, bh, c1[0][ni], 0, 0, 0);
                c1[1][ni] = __builtin_amdgcn_mfma_f32_16x16x32_bf16(a1h1, bh, c1[1][ni], 0, 0, 0);
                c1[1][ni] = __builtin_amdgcn_mfma_f32_16x16x32_bf16(a1h1, bl, c1[1][ni], 0, 0, 0);
                c1[1][ni] = __builtin_amdgcn_mfma_f32_16x16x32_bf16(a1l1, bh, c1[1][ni], 0, 0, 0);
            }
        }
        // effective bias (t folded) per (m, r)
        float eb[2][4];
#pragma unroll
        for (int m = 0; m < 2; m++)
#pragma unroll
            for (int r = 0; r < 4; r++) {
                int oc = kc * 32 + m * 16 + kl4 + r;
                eb[m][r] = b1p[oc] + t * W1t[oc * 33];
            }
        __syncthreads();   // conv3(kc-1) done reading X
        // softplus + pack + write X (border rows/cols zeroed)
#pragma unroll
        for (int ni = 0; ni < 3; ni++) {
            int n = wid * 3 + ni;
            if (n >= 22) continue;
            int ppad = n * 16 + ln15;
            if (ppad < 340) {
                int prow = ppad / 34, pcol = ppad - prow * 34;
                bool zero = (pcol == 0) || (pcol == 33) ||
                            (strip == 0 && prow == 0) || (strip == 3 && prow == 9);
#pragma unroll
                for (int m = 0; m < 2; m++) {
                    float v[4];
#pragma unroll
                    for (int r = 0; r < 4; r++)
                        v[r] = zero ? 0.f : softplus_f(c1[m][ni][r] + eb[m][r]);
                    unsigned int h01, l01, h23, l23;
                    pack2(v[0], v[1], h01, l01);
                    pack2(v[2], v[3], h23, l23);
                    int off = ppad * XP + m * 16 + kl4;
                    *(uint2*)(xh + off) = make_uint2(h01, h23);
                    *(uint2*)(xl + off) = make_uint2(l01, l23);
                }
            }
        }
        __syncthreads();
        // conv3 partial: 9 shifts
#pragma unroll
        for (int sh = 0; sh < 9; sh++) {
            const size_t wbase = ((size_t)(sh * 4 + kc) * 8 + wocg) * 512 + lane * 8;
            bf16x8 ah0 = *(const bf16x8*)(w2h + wbase);
            bf16x8 al0 = *(const bf16x8*)(w2l + wbase);
            bf16x8 ah1 = *(const bf16x8*)(w2h + wbase + 512);
            bf16x8 al1 = *(const bf16x8*)(w2l + wbase + 512);
            const int soff = ((sh / 3) * 34 + (sh % 3)) * XP;
#pragma unroll
            for (int f = 0; f < 8; f++) {
                bf16x8 bh = *(const bf16x8*)(xh + boff[f] + soff);
                bf16x8 bl = *(const bf16x8*)(xl + boff[f] + soff);
                acc[0][f] = __builtin_amdgcn_mfma_f32_16x16x32_bf16(ah0, bh, acc[0][f], 0, 0, 0);
                acc[0][f] = __builtin_amdgcn_mfma_f32_16x16x32_bf16(ah0, bl, acc[0][f], 0, 0, 0);
                acc[0][f] = __builtin_amdgcn_mfma_f32_16x16x32_bf16(al0, bh, acc[0][f], 0, 0, 0);
                acc[1][f] = __builtin_amdgcn_mfma_f32_16x16x32_bf16(ah1, bh, acc[1][f], 0, 0, 0);
                acc[1][f] = __builtin_amdgcn_mfma_f32_16x16x32_bf16(ah1, bl, acc[1][f], 0, 0, 0);
                acc[1][f] = __builtin_amdgcn_mfma_f32_16x16x32_bf16(al1, bh, acc[1][f], 0, 0, 0);
            }
        }
    }

    // ---- convw3 + RK4 epilogue, per 64-px quarter ----
    float bb2[2][4];
#pragma unroll
    for (int o2 = 0; o2 < 2; o2++)
#pragma unroll
        for (int r = 0; r < 4; r++)
            bb2[o2][r] = b2p[(wocg + o2) * 16 + kl4 + r];

    const size_t obB = (size_t)b * HCn * NPX + strip * 256;
    const int m3 = wid & 1, n4 = wid >> 1;
    float bb3[4];
#pragma unroll
    for (int r = 0; r < 4; r++) bb3[r] = b3p[m3 * 16 + kl4 + r];

#pragma unroll
    for (int q = 0; q < 4; q++) {
        __syncthreads();   // q=0: conv3 done (zin free); q>0: prev quarter read done
        if ((wid >> 2) == (q >> 1)) {      // owning px-half group writes h2 quarter
            const int fq = (q & 1) * 4;
#pragma unroll
            for (int o2 = 0; o2 < 2; o2++)
#pragma unroll
                for (int f2 = 0; f2 < 4; f2++) {
                    f32x4 a = acc[o2][fq + f2];
                    float v[4];
#pragma unroll
                    for (int r = 0; r < 4; r++) v[r] = softplus_f(a[r] + bb2[o2][r]);
                    unsigned int h01, l01, h23, l23;
                    pack2(v[0], v[1], h01, l01);
                    pack2(v[2], v[3], h23, l23);
                    int off = (f2 * 16 + ln15) * H2P + (wocg + o2) * 16 + kl4;
                    *(uint2*)(h2qh + off) = make_uint2(h01, h23);
                    *(uint2*)(h2ql + off) = make_uint2(l01, l23);
                }
        }
        __syncthreads();
        // convw3: [32st x 128K] x h2q[128K x 64px]; 1 tile per wave
        f32x4 c3 = (f32x4)(0.f);
#pragma unroll
        for (int kk = 0; kk < 4; kk++) {
            const unsigned short* a3hb = w3h + (size_t)(m3 * 4 + kk) * 512 + lane * 8;
            const unsigned short* a3lb = w3l + (size_t)(m3 * 4 + kk) * 512 + lane * 8;
            bf16x8 a3h = *(const bf16x8*)a3hb;
            bf16x8 a3l = *(const bf16x8*)a3lb;
            bf16x8 bh = *(const bf16x8*)(h2qh + (n4 * 16 + ln15) * H2P + kk * 32 + kl8);
            bf16x8 bl = *(const bf16x8*)(h2ql + (n4 * 16 + ln15) * H2P + kk * 32 + kl8);
            c3 = __builtin_amdgcn_mfma_f32_16x16x32_bf16(a3h, bh, c3, 0, 0, 0);
            c3 = __builtin_amdgcn_mfma_f32_16x16x32_bf16(a3h, bl, c3, 0, 0, 0);
            c3 = __builtin_amdgcn_mfma_f32_16x16x32_bf16(a3l, bh, c3, 0, 0, 0);
        }
#pragma unroll
        for (int r = 0; r < 4; r++) {
            int st = m3 * 16 + kl4 + r;
            float v = tanhf(c3[r] + bb3[r]);
            size_t i = obB + (size_t)st * NPX + q * 64 + n4 * 16 + ln15;
            if (mode == 0)      { kb_out[i] = v; accb[i] = v; }
            else if (mode == 1) { kb_out[i] = v; accb[i] += 2.f * v; }
            else                { z_out[i] = z_in[i] + (accb[i] + v) * (1.f / 6.f); }
        }
    }
}

// ---------------- readout ----------------
__global__ __launch_bounds__(256) void k_logits(
    const float* __restrict__ z, const float* __restrict__ roW,
    const float* __restrict__ rob, float* __restrict__ logits)
{
    const int b = blockIdx.x, tid = threadIdx.x;
    float p[NCLS];
#pragma unroll
    for (int c = 0; c < NCLS; c++) p[c] = 0.f;
    const float* zp = z + (size_t)b * 32768;
    for (int i = tid; i < 32768; i += 256) {
        float zv = zp[i];
#pragma unroll
        for (int c = 0; c < NCLS; c++) p[c] = fmaf(zv, roW[(size_t)c * 32768 + i], p[c]);
    }
#pragma unroll
    for (int c = 0; c < NCLS; c++)
        for (int off = 32; off > 0; off >>= 1) p[c] += __shfl_down(p[c], off, 64);
    __shared__ float red[4][NCLS];
    int wid = tid >> 6, lane = tid & 63;
    if (lane == 0)
#pragma unroll
        for (int c = 0; c < NCLS; c++) red[wid][c] = p[c];
    __syncthreads();
    if (tid < NCLS) {
        float s = red[0][tid] + red[1][tid] + red[2][tid] + red[3][tid] + rob[tid];
        logits[b * NCLS + tid] = s;
    }
}

// ---------------- loss + accuracy ----------------
__global__ __launch_bounds__(128) void k_loss(
    const float* __restrict__ logits, const int* __restrict__ y,
    float* __restrict__ out)
{
    const int b = threadIdx.x;   // 0..127
    float l[NCLS];
#pragma unroll
    for (int c = 0; c < NCLS; c++) l[c] = logits[b * NCLS + c];
    float m = l[0]; int am = 0;
#pragma unroll
    for (int c = 1; c < NCLS; c++) if (l[c] > m) { m = l[c]; am = c; }
    float s = 0.f;
#pragma unroll
    for (int c = 0; c < NCLS; c++) s += expf(l[c] - m);
    float lse = m + logf(s);
    int yy = y[b];
    float loss_b = lse - l[yy];
    float corr = (am == yy) ? 1.f : 0.f;
    for (int off = 32; off > 0; off >>= 1) {
        loss_b += __shfl_down(loss_b, off, 64);
        corr   += __shfl_down(corr,   off, 64);
    }
    __shared__ float sl[2], sc[2];
    if ((b & 63) == 0) { sl[b >> 6] = loss_b; sc[b >> 6] = corr; }
    __syncthreads();
    if (b == 0) {
        out[0] = (sl[0] + sl[1]) / (float)BN;
        out[1] = sc[0] + sc[1];
    }
}

extern "C" void kernel_launch(void* const* d_in, const int* in_sizes, int n_in,
                              void* d_out, int out_size, void* d_ws, size_t ws_size,
                              hipStream_t stream) {
    const float* x   = (const float*)d_in[0];
    const int*   y   = (const int*)  d_in[1];
    const float* aW  = (const float*)d_in[2];
    const float* ab  = (const float*)d_in[3];
    const float* W1  = (const float*)d_in[4];
    const float* b1  = (const float*)d_in[5];
    const float* W2  = (const float*)d_in[6];
    const float* b2  = (const float*)d_in[7];
    const float* W3  = (const float*)d_in[8];
    const float* b3  = (const float*)d_in[9];
    const float* roW = (const float*)d_in[10];
    const float* rob = (const float*)d_in[11];
    float* out = (float*)d_out;
    float* ws  = (float*)d_ws;

    const size_t ZSZ = (size_t)BN * HCn * NPX;    // 4.19M floats
    float* zb0    = ws;
    float* zb1    = zb0 + ZSZ;
    float* kb0    = zb1 + ZSZ;
    float* kb1    = kb0 + ZSZ;
    float* accb   = kb1 + ZSZ;
    float* logits = accb + ZSZ;
    unsigned short* w2h = (unsigned short*)(logits + 4096);
    unsigned short* w2l = w2h + 589824;
    unsigned short* w1h = w2l + 589824;
    unsigned short* w1l = w1h + 16384;
    unsigned short* w3h = w1l + 16384;
    unsigned short* w3l = w3h + 16384;

    k_packW2<<<2304, 256, 0, stream>>>(W2, w2h, w2l);
    k_packW1<<<64, 256, 0, stream>>>(W1, w1h, w1l);
    k_packW3<<<64, 256, 0, stream>>>(W3, w3h, w3l);
    k_aug<<<BN, 256, 0, stream>>>(x, aW, ab, zb0);

    float* zA = zb0;
    float* zB = zb1;
    for (int p = 0; p < PN; p++) {
        for (int e = 0; e < 4; e++) {
            const int idx = (e == 3 && p + 1 < PN) ? p + 1 : p;
            const float t = (float)p + (e == 0 ? 0.f : (e == 3 ? 1.f : 0.5f));
            const float alpha = (e == 0) ? 0.f : (e == 3 ? 1.f : 0.5f);
            const int mode = (e == 0) ? 0 : (e == 3 ? 2 : 1);
            const float* kbin = (e == 2) ? kb1 : kb0;   // e1:kb0 e2:kb1 e3:kb0
            float* kbout = (e == 1) ? kb1 : kb0;        // e0:kb0 e1:kb1 e2:kb0
            k_fused<<<dim3(4, BN), 512, 0, stream>>>(
                zA, kbin, alpha,
                b1 + (size_t)idx * HHCn, W1 + (size_t)idx * HHCn * 33, t,
                w1h + (size_t)idx * 4096, w1l + (size_t)idx * 4096,
                w2h + (size_t)idx * 147456, w2l + (size_t)idx * 147456,
                b2 + (size_t)idx * HHCn,
                w3h + (size_t)idx * 4096, w3l + (size_t)idx * 4096,
                b3 + (size_t)idx * HCn,
                kbout, accb, zB, mode);
        }
        float* tmp = zA; zA = zB; zB = tmp;
    }

    k_logits<<<BN, 256, 0, stream>>>(zA, roW, rob, logits);
    k_loss<<<1, 128, 0, stream>>>(logits, y, out);
}

// Round 6
// 4055.665 us; speedup vs baseline: 3.7030x; 1.0286x over previous
//
#include <hip/hip_runtime.h>
#include <math.h>

// Problem constants
#define BN   128      // batch
#define CIN  3
#define HCn  32       // hidden channels (ODE state)
#define HHCn 128      // inner hidden channels
#define NPX  1024     // 32*32
#define PN   4        // pieces
#define NCLS 10

// LDS plane layout: a 32-ic x 340-px tile is stored as 4 planes of 8 ic.
// Plane rows are 16B (8 ushorts): b128 read = one full row; lane-group g
// (lane>>4) reads plane g. Bank-exact: stride 16B tiles 256B per 16 lanes.
#define PLROW 8       // ushorts per plane row (8 ic)
#define PLSZ  2720    // ushorts per plane (340 rows * 8)
#define H2P   136     // h2 quarter pitch (ushorts): 272B rows

typedef short bf16x8 __attribute__((ext_vector_type(8)));
typedef float f32x4  __attribute__((ext_vector_type(4)));

__device__ __forceinline__ float softplus_f(float x) {
    return fmaxf(x, 0.f) + log1pf(expf(-fabsf(x)));
}
__device__ __forceinline__ unsigned int f2bf(float f) {   // RNE fp32->bf16 bits
    unsigned int u = __float_as_uint(f);
    return (u + 0x7fffu + ((u >> 16) & 1u)) >> 16;
}
__device__ __forceinline__ float bf2f(unsigned int h) {
    return __uint_as_float(h << 16);
}
__device__ __forceinline__ void pack2(float a, float b, unsigned int& hi, unsigned int& lo) {
    unsigned int ha = f2bf(a), hb = f2bf(b);
    unsigned int la = f2bf(a - bf2f(ha)), lb = f2bf(b - bf2f(hb));
    hi = ha | (hb << 16);
    lo = la | (lb << 16);
}

// ---------------- augment: z = x * aug_W^T + aug_b  (1x1 conv 3->32) ----------------
__global__ __launch_bounds__(256) void k_aug(
    const float* __restrict__ x, const float* __restrict__ aW,
    const float* __restrict__ ab, float* __restrict__ z)
{
    const int b = blockIdx.x, tid = threadIdx.x;
    const size_t xb = (size_t)b * CIN * NPX;
    const size_t zb = (size_t)b * HCn * NPX;
    float xv[CIN][4];
#pragma unroll
    for (int c = 0; c < CIN; c++)
#pragma unroll
        for (int j = 0; j < 4; j++)
            xv[c][j] = x[xb + c * NPX + tid + 256 * j];
    for (int o = 0; o < HCn; o++) {
        float w0 = aW[o * 3], w1 = aW[o * 3 + 1], w2 = aW[o * 3 + 2], bb = ab[o];
#pragma unroll
        for (int j = 0; j < 4; j++) {
            float v = fmaf(w0, xv[0][j], fmaf(w1, xv[1][j], fmaf(w2, xv[2][j], bb)));
            z[zb + (size_t)o * NPX + tid + 256 * j] = v;
        }
    }
}

// ---------------- pack W2 into MFMA A-frag order, bf16 hi/lo ----------------
// layout: [p][sh][kc][ocg][lane][j] ; oc=ocg*16+(lane&15), ic=kc*32+(lane>>4)*8+j
__global__ __launch_bounds__(256) void k_packW2(
    const float* __restrict__ W2, unsigned short* __restrict__ whi,
    unsigned short* __restrict__ wlo)
{
    int t = blockIdx.x * 256 + threadIdx.x;          // < 589824
    int j    = t & 7;
    int lane = (t >> 3) & 63;
    int ocg  = (t >> 9) & 7;
    int kc   = (t >> 12) & 3;
    int p9s  = t >> 14;                              // p*9 + sh
    int sh = p9s % 9, p = p9s / 9;
    int dy = sh / 3, dx = sh % 3;
    int oc = ocg * 16 + (lane & 15);
    int ic = kc * 32 + (lane >> 4) * 8 + j;
    float v = W2[((((size_t)p * HHCn + oc) * HHCn + ic) * 3 + dy) * 3 + dx];
    unsigned int hi = f2bf(v);
    whi[t] = (unsigned short)hi;
    wlo[t] = (unsigned short)f2bf(v - bf2f(hi));
}

// ---------------- pack W1 (skip t-col): [p][kc][m][lane][j] -----------------
__global__ __launch_bounds__(256) void k_packW1(
    const float* __restrict__ W1, unsigned short* __restrict__ whi,
    unsigned short* __restrict__ wlo)
{
    int t = blockIdx.x * 256 + threadIdx.x;          // < 16384
    int j = t & 7, lane = (t >> 3) & 63, m = (t >> 9) & 1, kc = (t >> 10) & 3, p = t >> 12;
    int oc = kc * 32 + m * 16 + (lane & 15);
    int ic = (lane >> 4) * 8 + j;
    float v = W1[((size_t)p * HHCn + oc) * 33 + 1 + ic];
    unsigned int hi = f2bf(v);
    whi[t] = (unsigned short)hi;
    wlo[t] = (unsigned short)f2bf(v - bf2f(hi));
}

// ---------------- pack W3: [p][m][kk][lane][j] ------------------------------
__global__ __launch_bounds__(256) void k_packW3(
    const float* __restrict__ W3, unsigned short* __restrict__ whi,
    unsigned short* __restrict__ wlo)
{
    int t = blockIdx.x * 256 + threadIdx.x;          // < 16384
    int j = t & 7, lane = (t >> 3) & 63, kk = (t >> 9) & 3, m = (t >> 11) & 1, p = t >> 12;
    int st = m * 16 + (lane & 15);
    int ic = kk * 32 + (lane >> 4) * 8 + j;
    float v = W3[((size_t)p * HCn + st) * HHCn + ic];
    unsigned int hi = f2bf(v);
    whi[t] = (unsigned short)hi;
    wlo[t] = (unsigned short)f2bf(v - bf2f(hi));
}

// ---------------- fused f-eval: conv1 -> conv3x3 -> convw3 + RK4 ------------
// grid (4 strips, BN), 512 thr (8 waves). All GEMMs via mfma_f32_16x16x32_bf16
// with hi/lo 3-split. h1/h2 never leave the block (LDS/registers).
// launch_bounds(512,1): LDS (87KB) limits to 1 block/CU anyway; do NOT cap
// VGPRs at 128 — R4's (512,2) spilled the MFMA accumulator to scratch.
__global__ __launch_bounds__(512, 1) void k_fused(
    const float* __restrict__ z_in, const float* __restrict__ kb_in, float alpha,
    const float* __restrict__ b1p, const float* __restrict__ W1t, float t,
    const unsigned short* __restrict__ w1h, const unsigned short* __restrict__ w1l,
    const unsigned short* __restrict__ w2h, const unsigned short* __restrict__ w2l,
    const float* __restrict__ b2p,
    const unsigned short* __restrict__ w3h, const unsigned short* __restrict__ w3l,
    const float* __restrict__ b3p,
    float* __restrict__ kb_out, float* __restrict__ accb, float* __restrict__ z_out,
    int mode)
{
    const int strip = blockIdx.x, b = blockIdx.y;
    const int tid = threadIdx.x, lane = tid & 63, wid = tid >> 6;
    const int ln15 = lane & 15, lg = lane >> 4;
    const int kl8 = lg * 8, kl4 = lg * 4;

    __shared__ __align__(16) unsigned short S[43520];   // 87.04 KB
    unsigned short* zinh = S;                            // 4 planes * 2720
    unsigned short* zinl = S + 10880;
    unsigned short* xh   = S + 21760;
    unsigned short* xl   = S + 32640;
    unsigned short* h2qh = S;                            // alias zin (freed)
    unsigned short* h2ql = S + 8704;                     // 64*136

    const size_t zbB = (size_t)b * HCn * NPX;
    const int strip0 = strip * 8;

    // ---- phase 0: stage zin = bf16hl(z + alpha*k), 32ic x 340 padded px ----
    {
        const int ic0 = wid * 4;                 // 4 ic per wave
        const int pl  = wid >> 1;                // target plane
        const int sl  = (wid & 1) * 4;           // ushort slot in 8-ush row
#pragma unroll
        for (int it = 0; it < 6; it++) {
            int ppad = it * 64 + lane;
            int prow = ppad / 34, pcol = ppad - prow * 34;
            int gy = strip0 + prow - 1, gx = pcol - 1;
            bool okm = (ppad < 340) && (gy >= 0) && (gy < 32) && (gx >= 0) && (gx < 32);
            int gsrc = gy * 32 + gx;
            float v[4];
#pragma unroll
            for (int c = 0; c < 4; c++)
                v[c] = okm ? z_in[zbB + (size_t)(ic0 + c) * NPX + gsrc] : 0.f;
            if (alpha != 0.f) {
#pragma unroll
                for (int c = 0; c < 4; c++)
                    if (okm) v[c] = fmaf(alpha, kb_in[zbB + (size_t)(ic0 + c) * NPX + gsrc], v[c]);
            }
            unsigned int h01, l01, h23, l23;
            pack2(v[0], v[1], h01, l01);
            pack2(v[2], v[3], h23, l23);
            if (ppad < 340) {
                int off = pl * PLSZ + ppad * PLROW + sl;
                *(uint2*)(zinh + off) = make_uint2(h01, h23);
                *(uint2*)(zinl + off) = make_uint2(l01, l23);
            }
        }
    }
    __syncthreads();

    const int wocg = (wid & 3) * 2;          // conv3 role: oc pair base
    const int wph  = (wid >> 2) * 128;       // conv3 role: px half
    int boff[8];                             // X read base per n-frag (ushorts)
#pragma unroll
    for (int f = 0; f < 8; f++) {
        int pxl = wph + f * 16 + ln15;
        boff[f] = lg * PLSZ + ((pxl >> 5) * 34 + (pxl & 31)) * PLROW;
    }

    f32x4 acc[2][8];
#pragma unroll
    for (int o = 0; o < 2; o++)
#pragma unroll
        for (int f = 0; f < 8; f++) acc[o][f] = (f32x4)(0.f);

    // ---- main loop: per 32-ic chunk: conv1 MFMA -> X LDS -> conv3 MFMA ----
    for (int kc = 0; kc < 4; kc++) {
        // conv1: [32oc x 32K] x zin[32K x 352px]; wave handles n = wid*3..+2
        const unsigned short* w1hb = w1h + (size_t)kc * 1024 + lane * 8;
        const unsigned short* w1lb = w1l + (size_t)kc * 1024 + lane * 8;
        bf16x8 a1h0 = *(const bf16x8*)w1hb,          a1h1 = *(const bf16x8*)(w1hb + 512);
        bf16x8 a1l0 = *(const bf16x8*)w1lb,          a1l1 = *(const bf16x8*)(w1lb + 512);
        f32x4 c1[2][3];
#pragma unroll
        for (int m = 0; m < 2; m++)
#pragma unroll
            for (int ni = 0; ni < 3; ni++) c1[m][ni] = (f32x4)(0.f);
#pragma unroll
        for (int ni = 0; ni < 3; ni++) {
            int n = wid * 3 + ni;
            if (n < 22) {
                int roff = lg * PLSZ + (n * 16 + ln15) * PLROW;
                bf16x8 bh = *(const bf16x8*)(zinh + roff);
                bf16x8 bl = *(const bf16x8*)(zinl + roff);
                c1[0][ni] = __builtin_amdgcn_mfma_f32_16x16x32_bf16(a1h0, bh, c1[0][ni], 0, 0, 0);
                c1[0][ni] = __builtin_amdgcn_mfma_f32_16x16x32_bf16(a1h0, bl, c1[0][ni], 0, 0, 0);
                c1[0][ni] = __builtin_amdgcn_mfma_f32_16x16x32_bf16(a1l0, bh, c1[0][ni], 0, 0, 0);
                c1[1][ni] = __builtin_amdgcn_mfma_f32_16x16x32_bf16(a1h1, bh, c1[1][ni], 0, 0, 0);
                c1[1][ni] = __builtin_amdgcn_mfma_f32_16x16x32_bf16(a1h1, bl, c1[1][ni], 0, 0, 0);
                c1[1][ni] = __builtin_amdgcn_mfma_f32_16x16x32_bf16(a1l1, bh, c1[1][ni], 0, 0, 0);
            }
        }
        // effective bias (t folded) per (m, r)
        float eb[2][4];
#pragma unroll
        for (int m = 0; m < 2; m++)
#pragma unroll
            for (int r = 0; r < 4; r++) {
                int oc = kc * 32 + m * 16 + kl4 + r;
                eb[m][r] = b1p[oc] + t * W1t[oc * 33];
            }
        __syncthreads();   // conv3(kc-1) done reading X
        // softplus + pack + write X (border rows/cols zeroed)
        // thread owns within-chunk ic = m*16 + kl4 + r -> plane m*2+(kl4>>3), slot kl4&7
#pragma unroll
        for (int ni = 0; ni < 3; ni++) {
            int n = wid * 3 + ni;
            if (n >= 22) continue;
            int ppad = n * 16 + ln15;
            if (ppad < 340) {
                int prow = ppad / 34, pcol = ppad - prow * 34;
                bool zero = (pcol == 0) || (pcol == 33) ||
                            (strip == 0 && prow == 0) || (strip == 3 && prow == 9);
#pragma unroll
                for (int m = 0; m < 2; m++) {
                    float v[4];
#pragma unroll
                    for (int r = 0; r < 4; r++)
                        v[r] = zero ? 0.f : softplus_f(c1[m][ni][r] + eb[m][r]);
                    unsigned int h01, l01, h23, l23;
                    pack2(v[0], v[1], h01, l01);
                    pack2(v[2], v[3], h23, l23);
                    int off = (m * 2 + (kl4 >> 3)) * PLSZ + ppad * PLROW + (kl4 & 7);
                    *(uint2*)(xh + off) = make_uint2(h01, h23);
                    *(uint2*)(xl + off) = make_uint2(l01, l23);
                }
            }
        }
        __syncthreads();
        // conv3 partial: 9 shifts
#pragma unroll
        for (int sh = 0; sh < 9; sh++) {
            const size_t wbase = ((size_t)(sh * 4 + kc) * 8 + wocg) * 512 + lane * 8;
            bf16x8 ah0 = *(const bf16x8*)(w2h + wbase);
            bf16x8 al0 = *(const bf16x8*)(w2l + wbase);
            bf16x8 ah1 = *(const bf16x8*)(w2h + wbase + 512);
            bf16x8 al1 = *(const bf16x8*)(w2l + wbase + 512);
            const int soff = ((sh / 3) * 34 + (sh % 3)) * PLROW;
#pragma unroll
            for (int f = 0; f < 8; f++) {
                bf16x8 bh = *(const bf16x8*)(xh + boff[f] + soff);
                bf16x8 bl = *(const bf16x8*)(xl + boff[f] + soff);
                acc[0][f] = __builtin_amdgcn_mfma_f32_16x16x32_bf16(ah0, bh, acc[0][f], 0, 0, 0);
                acc[0][f] = __builtin_amdgcn_mfma_f32_16x16x32_bf16(ah0, bl, acc[0][f], 0, 0, 0);
                acc[0][f] = __builtin_amdgcn_mfma_f32_16x16x32_bf16(al0, bh, acc[0][f], 0, 0, 0);
                acc[1][f] = __builtin_amdgcn_mfma_f32_16x16x32_bf16(ah1, bh, acc[1][f], 0, 0, 0);
                acc[1][f] = __builtin_amdgcn_mfma_f32_16x16x32_bf16(ah1, bl, acc[1][f], 0, 0, 0);
                acc[1][f] = __builtin_amdgcn_mfma_f32_16x16x32_bf16(al1, bh, acc[1][f], 0, 0, 0);
            }
        }
    }

    // ---- convw3 + RK4 epilogue, per 64-px quarter ----
    float bb2[2][4];
#pragma unroll
    for (int o2 = 0; o2 < 2; o2++)
#pragma unroll
        for (int r = 0; r < 4; r++)
            bb2[o2][r] = b2p[(wocg + o2) * 16 + kl4 + r];

    const size_t obB = (size_t)b * HCn * NPX + strip * 256;
    const int m3 = wid & 1, n4 = wid >> 1;
    float bb3[4];
#pragma unroll
    for (int r = 0; r < 4; r++) bb3[r] = b3p[m3 * 16 + kl4 + r];

#pragma unroll
    for (int q = 0; q < 4; q++) {
        __syncthreads();   // q=0: conv3 done (zin free); q>0: prev quarter read done
        if ((wid >> 2) == (q >> 1)) {      // owning px-half group writes h2 quarter
            const int fq = (q & 1) * 4;
#pragma unroll
            for (int o2 = 0; o2 < 2; o2++)
#pragma unroll
                for (int f2 = 0; f2 < 4; f2++) {
                    f32x4 a = acc[o2][fq + f2];
                    float v[4];
#pragma unroll
                    for (int r = 0; r < 4; r++) v[r] = softplus_f(a[r] + bb2[o2][r]);
                    unsigned int h01, l01, h23, l23;
                    pack2(v[0], v[1], h01, l01);
                    pack2(v[2], v[3], h23, l23);
                    int off = (f2 * 16 + ln15) * H2P + (wocg + o2) * 16 + kl4;
                    *(uint2*)(h2qh + off) = make_uint2(h01, h23);
                    *(uint2*)(h2ql + off) = make_uint2(l01, l23);
                }
        }
        __syncthreads();
        // convw3: [32st x 128K] x h2q[128K x 64px]; 1 tile per wave
        f32x4 c3 = (f32x4)(0.f);
#pragma unroll
        for (int kk = 0; kk < 4; kk++) {
            const unsigned short* a3hb = w3h + (size_t)(m3 * 4 + kk) * 512 + lane * 8;
            const unsigned short* a3lb = w3l + (size_t)(m3 * 4 + kk) * 512 + lane * 8;
            bf16x8 a3h = *(const bf16x8*)a3hb;
            bf16x8 a3l = *(const bf16x8*)a3lb;
            bf16x8 bh = *(const bf16x8*)(h2qh + (n4 * 16 + ln15) * H2P + kk * 32 + kl8);
            bf16x8 bl = *(const bf16x8*)(h2ql + (n4 * 16 + ln15) * H2P + kk * 32 + kl8);
            c3 = __builtin_amdgcn_mfma_f32_16x16x32_bf16(a3h, bh, c3, 0, 0, 0);
            c3 = __builtin_amdgcn_mfma_f32_16x16x32_bf16(a3h, bl, c3, 0, 0, 0);
            c3 = __builtin_amdgcn_mfma_f32_16x16x32_bf16(a3l, bh, c3, 0, 0, 0);
        }
#pragma unroll
        for (int r = 0; r < 4; r++) {
            int st = m3 * 16 + kl4 + r;
            float v = tanhf(c3[r] + bb3[r]);
            size_t i = obB + (size_t)st * NPX + q * 64 + n4 * 16 + ln15;
            if (mode == 0)      { kb_out[i] = v; accb[i] = v; }
            else if (mode == 1) { kb_out[i] = v; accb[i] += 2.f * v; }
            else                { z_out[i] = z_in[i] + (accb[i] + v) * (1.f / 6.f); }
        }
    }
}

// ---------------- readout ----------------
__global__ __launch_bounds__(256) void k_logits(
    const float* __restrict__ z, const float* __restrict__ roW,
    const float* __restrict__ rob, float* __restrict__ logits)
{
    const int b = blockIdx.x, tid = threadIdx.x;
    float p[NCLS];
#pragma unroll
    for (int c = 0; c < NCLS; c++) p[c] = 0.f;
    const float* zp = z + (size_t)b * 32768;
    for (int i = tid; i < 32768; i += 256) {
        float zv = zp[i];
#pragma unroll
        for (int c = 0; c < NCLS; c++) p[c] = fmaf(zv, roW[(size_t)c * 32768 + i], p[c]);
    }
#pragma unroll
    for (int c = 0; c < NCLS; c++)
        for (int off = 32; off > 0; off >>= 1) p[c] += __shfl_down(p[c], off, 64);
    __shared__ float red[4][NCLS];
    int wid = tid >> 6, lane = tid & 63;
    if (lane == 0)
#pragma unroll
        for (int c = 0; c < NCLS; c++) red[wid][c] = p[c];
    __syncthreads();
    if (tid < NCLS) {
        float s = red[0][tid] + red[1][tid] + red[2][tid] + red[3][tid] + rob[tid];
        logits[b * NCLS + tid] = s;
    }
}

// ---------------- loss + accuracy ----------------
__global__ __launch_bounds__(128) void k_loss(
    const float* __restrict__ logits, const int* __restrict__ y,
    float* __restrict__ out)
{
    const int b = threadIdx.x;   // 0..127
    float l[NCLS];
#pragma unroll
    for (int c = 0; c < NCLS; c++) l[c] = logits[b * NCLS + c];
    float m = l[0]; int am = 0;
#pragma unroll
    for (int c = 1; c < NCLS; c++) if (l[c] > m) { m = l[c]; am = c; }
    float s = 0.f;
#pragma unroll
    for (int c = 0; c < NCLS; c++) s += expf(l[c] - m);
    float lse = m + logf(s);
    int yy = y[b];
    float loss_b = lse - l[yy];
    float corr = (am == yy) ? 1.f : 0.f;
    for (int off = 32; off > 0; off >>= 1) {
        loss_b += __shfl_down(loss_b, off, 64);
        corr   += __shfl_down(corr,   off, 64);
    }
    __shared__ float sl[2], sc[2];
    if ((b & 63) == 0) { sl[b >> 6] = loss_b; sc[b >> 6] = corr; }
    __syncthreads();
    if (b == 0) {
        out[0] = (sl[0] + sl[1]) / (float)BN;
        out[1] = sc[0] + sc[1];
    }
}

extern "C" void kernel_launch(void* const* d_in, const int* in_sizes, int n_in,
                              void* d_out, int out_size, void* d_ws, size_t ws_size,
                              hipStream_t stream) {
    const float* x   = (const float*)d_in[0];
    const int*   y   = (const int*)  d_in[1];
    const float* aW  = (const float*)d_in[2];
    const float* ab  = (const float*)d_in[3];
    const float* W1  = (const float*)d_in[4];
    const float* b1  = (const float*)d_in[5];
    const float* W2  = (const float*)d_in[6];
    const float* b2  = (const float*)d_in[7];
    const float* W3  = (const float*)d_in[8];
    const float* b3  = (const float*)d_in[9];
    const float* roW = (const float*)d_in[10];
    const float* rob = (const float*)d_in[11];
    float* out = (float*)d_out;
    float* ws  = (float*)d_ws;

    const size_t ZSZ = (size_t)BN * HCn * NPX;    // 4.19M floats
    float* zb0    = ws;
    float* zb1    = zb0 + ZSZ;
    float* kb0    = zb1 + ZSZ;
    float* kb1    = kb0 + ZSZ;
    float* accb   = kb1 + ZSZ;
    float* logits = accb + ZSZ;
    unsigned short* w2h = (unsigned short*)(logits + 4096);
    unsigned short* w2l = w2h + 589824;
    unsigned short* w1h = w2l + 589824;
    unsigned short* w1l = w1h + 16384;
    unsigned short* w3h = w1l + 16384;
    unsigned short* w3l = w3h + 16384;

    k_packW2<<<2304, 256, 0, stream>>>(W2, w2h, w2l);
    k_packW1<<<64, 256, 0, stream>>>(W1, w1h, w1l);
    k_packW3<<<64, 256, 0, stream>>>(W3, w3h, w3l);
    k_aug<<<BN, 256, 0, stream>>>(x, aW, ab, zb0);

    float* zA = zb0;
    float* zB = zb1;
    for (int p = 0; p < PN; p++) {
        for (int e = 0; e < 4; e++) {
            const int idx = (e == 3 && p + 1 < PN) ? p + 1 : p;
            const float t = (float)p + (e == 0 ? 0.f : (e == 3 ? 1.f : 0.5f));
            const float alpha = (e == 0) ? 0.f : (e == 3 ? 1.f : 0.5f);
            const int mode = (e == 0) ? 0 : (e == 3 ? 2 : 1);
            const float* kbin = (e == 2) ? kb1 : kb0;   // e1:kb0 e2:kb1 e3:kb0
            float* kbout = (e == 1) ? kb1 : kb0;        // e0:kb0 e1:kb1 e2:kb0
            k_fused<<<dim3(4, BN), 512, 0, stream>>>(
                zA, kbin, alpha,
                b1 + (size_t)idx * HHCn, W1 + (size_t)idx * HHCn * 33, t,
                w1h + (size_t)idx * 4096, w1l + (size_t)idx * 4096,
                w2h + (size_t)idx * 147456, w2l + (size_t)idx * 147456,
                b2 + (size_t)idx * HHCn,
                w3h + (size_t)idx * 4096, w3l + (size_t)idx * 4096,
                b3 + (size_t)idx * HCn,
                kbout, accb, zB, mode);
        }
        float* tmp = zA; zA = zB; zB = tmp;
    }

    k_logits<<<BN, 256, 0, stream>>>(zA, roW, rob, logits);
    k_loss<<<1, 128, 0, stream>>>(logits, y, out);
}

// Round 7
// 2178.575 us; speedup vs baseline: 6.8935x; 1.8616x over previous
//
#include <hip/hip_runtime.h>
#include <hip/hip_bf16.h>
#include <math.h>

// Problem constants
#define BN   128      // batch
#define CIN  3
#define HCn  32       // hidden channels (ODE state)
#define HHCn 128      // inner hidden channels
#define NPX  1024     // 32*32
#define PN   4        // pieces
#define NCLS 10

// LDS plane layout: a 32-ic x 340-px tile is stored as 4 planes of 8 ic.
// Plane rows are 16B (8 ushorts): b128 read = one full row.
#define PLROW 8       // ushorts per plane row (8 ic)
#define PLSZ  2720    // ushorts per plane (340 rows * 8)
#define H2P   136     // h2 quarter pitch (ushorts): 272B rows

typedef short bf16x8 __attribute__((ext_vector_type(8)));
typedef float f32x4  __attribute__((ext_vector_type(4)));

// ---- fast transcendentals (HW v_exp/v_log/v_rcp; err ~1e-7, threshold 0.2) ----
__device__ __forceinline__ float softplus_f(float x) {
    // max(x,0) + log(1 + exp(-|x|))
    return fmaxf(x, 0.f) + __logf(1.f + __expf(-fabsf(x)));
}
__device__ __forceinline__ float tanh_fast(float x) {
    float e = __expf(-2.f * fabsf(x));
    float r = 1.f - 2.f * e * __builtin_amdgcn_rcpf(1.f + e);   // tanh(|x|)
    unsigned u = (__float_as_uint(r) & 0x7fffffffu) | (__float_as_uint(x) & 0x80000000u);
    return __uint_as_float(u);
}
__device__ __forceinline__ unsigned int f2bf(float f) {   // RNE fp32->bf16 bits (pack kernels)
    unsigned int u = __float_as_uint(f);
    return (u + 0x7fffu + ((u >> 16) & 1u)) >> 16;
}
__device__ __forceinline__ float bf2f(unsigned int h) {
    return __uint_as_float(h << 16);
}
// hi/lo bf16 split of two floats via v_cvt_pk_bf16_f32 (compiler-emitted)
__device__ __forceinline__ void pack2(float a, float b, unsigned int& hi, unsigned int& lo) {
    __hip_bfloat162 h2 = __float22bfloat162_rn(float2{a, b});
    unsigned int h = *reinterpret_cast<unsigned int*>(&h2);
    float ha = __uint_as_float(h << 16);
    float hb = __uint_as_float(h & 0xffff0000u);
    __hip_bfloat162 l2 = __float22bfloat162_rn(float2{a - ha, b - hb});
    hi = h;
    lo = *reinterpret_cast<unsigned int*>(&l2);
}

// ---------------- augment: z = x * aug_W^T + aug_b  (1x1 conv 3->32) ----------------
__global__ __launch_bounds__(256) void k_aug(
    const float* __restrict__ x, const float* __restrict__ aW,
    const float* __restrict__ ab, float* __restrict__ z)
{
    const int b = blockIdx.x, tid = threadIdx.x;
    const size_t xb = (size_t)b * CIN * NPX;
    const size_t zb = (size_t)b * HCn * NPX;
    float xv[CIN][4];
#pragma unroll
    for (int c = 0; c < CIN; c++)
#pragma unroll
        for (int j = 0; j < 4; j++)
            xv[c][j] = x[xb + c * NPX + tid + 256 * j];
    for (int o = 0; o < HCn; o++) {
        float w0 = aW[o * 3], w1 = aW[o * 3 + 1], w2 = aW[o * 3 + 2], bb = ab[o];
#pragma unroll
        for (int j = 0; j < 4; j++) {
            float v = fmaf(w0, xv[0][j], fmaf(w1, xv[1][j], fmaf(w2, xv[2][j], bb)));
            z[zb + (size_t)o * NPX + tid + 256 * j] = v;
        }
    }
}

// ---------------- pack W2 into MFMA A-frag order, bf16 hi/lo ----------------
// layout: [p][sh][kc][ocg][lane][j] ; oc=ocg*16+(lane&15), ic=kc*32+(lane>>4)*8+j
__global__ __launch_bounds__(256) void k_packW2(
    const float* __restrict__ W2, unsigned short* __restrict__ whi,
    unsigned short* __restrict__ wlo)
{
    int t = blockIdx.x * 256 + threadIdx.x;          // < 589824
    int j    = t & 7;
    int lane = (t >> 3) & 63;
    int ocg  = (t >> 9) & 7;
    int kc   = (t >> 12) & 3;
    int p9s  = t >> 14;                              // p*9 + sh
    int sh = p9s % 9, p = p9s / 9;
    int dy = sh / 3, dx = sh % 3;
    int oc = ocg * 16 + (lane & 15);
    int ic = kc * 32 + (lane >> 4) * 8 + j;
    float v = W2[((((size_t)p * HHCn + oc) * HHCn + ic) * 3 + dy) * 3 + dx];
    unsigned int hi = f2bf(v);
    whi[t] = (unsigned short)hi;
    wlo[t] = (unsigned short)f2bf(v - bf2f(hi));
}

// ---------------- pack W1 (skip t-col): [p][kc][m][lane][j] -----------------
__global__ __launch_bounds__(256) void k_packW1(
    const float* __restrict__ W1, unsigned short* __restrict__ whi,
    unsigned short* __restrict__ wlo)
{
    int t = blockIdx.x * 256 + threadIdx.x;          // < 16384
    int j = t & 7, lane = (t >> 3) & 63, m = (t >> 9) & 1, kc = (t >> 10) & 3, p = t >> 12;
    int oc = kc * 32 + m * 16 + (lane & 15);
    int ic = (lane >> 4) * 8 + j;
    float v = W1[((size_t)p * HHCn + oc) * 33 + 1 + ic];
    unsigned int hi = f2bf(v);
    whi[t] = (unsigned short)hi;
    wlo[t] = (unsigned short)f2bf(v - bf2f(hi));
}

// ---------------- pack W3: [p][m][kk][lane][j] ------------------------------
__global__ __launch_bounds__(256) void k_packW3(
    const float* __restrict__ W3, unsigned short* __restrict__ whi,
    unsigned short* __restrict__ wlo)
{
    int t = blockIdx.x * 256 + threadIdx.x;          // < 16384
    int j = t & 7, lane = (t >> 3) & 63, kk = (t >> 9) & 3, m = (t >> 11) & 1, p = t >> 12;
    int st = m * 16 + (lane & 15);
    int ic = kk * 32 + (lane >> 4) * 8 + j;
    float v = W3[((size_t)p * HCn + st) * HHCn + ic];
    unsigned int hi = f2bf(v);
    whi[t] = (unsigned short)hi;
    wlo[t] = (unsigned short)f2bf(v - bf2f(hi));
}

// ---------------- fused f-eval: conv1 -> conv3x3 -> convw3 + RK4 ------------
// grid (4 strips, BN), 512 thr (8 waves). All GEMMs via mfma_f32_16x16x32_bf16
// with hi/lo 3-split. h1/h2 never leave the block (LDS/registers).
__global__ __launch_bounds__(512, 1) void k_fused(
    const float* __restrict__ z_in, const float* __restrict__ kb_in, float alpha,
    const float* __restrict__ b1p, const float* __restrict__ W1t, float t,
    const unsigned short* __restrict__ w1h, const unsigned short* __restrict__ w1l,
    const unsigned short* __restrict__ w2h, const unsigned short* __restrict__ w2l,
    const float* __restrict__ b2p,
    const unsigned short* __restrict__ w3h, const unsigned short* __restrict__ w3l,
    const float* __restrict__ b3p,
    float* __restrict__ kb_out, float* __restrict__ accb, float* __restrict__ z_out,
    int mode)
{
    const int strip = blockIdx.x, b = blockIdx.y;
    const int tid = threadIdx.x, lane = tid & 63, wid = tid >> 6;
    const int ln15 = lane & 15, lg = lane >> 4;
    const int kl8 = lg * 8, kl4 = lg * 4;

    __shared__ __align__(16) unsigned short S[43520];   // 87.04 KB
    unsigned short* zinh = S;                            // 4 planes * 2720
    unsigned short* zinl = S + 10880;
    unsigned short* xh   = S + 21760;
    unsigned short* xl   = S + 32640;
    unsigned short* h2qh = S;                            // alias zin (freed)
    unsigned short* h2ql = S + 8704;                     // 64*136

    const size_t zbB = (size_t)b * HCn * NPX;
    const int strip0 = strip * 8;

    // ---- phase 0: stage zin = bf16hl(z + alpha*k), 32ic x 340 padded px ----
    {
        const int ic0 = wid * 4;                 // 4 ic per wave
        const int pl  = wid >> 1;                // target plane
        const int sl  = (wid & 1) * 4;           // ushort slot in 8-ush row
#pragma unroll
        for (int it = 0; it < 6; it++) {
            int ppad = it * 64 + lane;
            int prow = ppad / 34, pcol = ppad - prow * 34;
            int gy = strip0 + prow - 1, gx = pcol - 1;
            bool okm = (ppad < 340) && (gy >= 0) && (gy < 32) && (gx >= 0) && (gx < 32);
            int gsrc = gy * 32 + gx;
            float v[4];
#pragma unroll
            for (int c = 0; c < 4; c++)
                v[c] = okm ? z_in[zbB + (size_t)(ic0 + c) * NPX + gsrc] : 0.f;
            if (alpha != 0.f) {
#pragma unroll
                for (int c = 0; c < 4; c++)
                    if (okm) v[c] = fmaf(alpha, kb_in[zbB + (size_t)(ic0 + c) * NPX + gsrc], v[c]);
            }
            unsigned int h01, l01, h23, l23;
            pack2(v[0], v[1], h01, l01);
            pack2(v[2], v[3], h23, l23);
            if (ppad < 340) {
                int off = pl * PLSZ + ppad * PLROW + sl;
                *(uint2*)(zinh + off) = make_uint2(h01, h23);
                *(uint2*)(zinl + off) = make_uint2(l01, l23);
            }
        }
    }
    __syncthreads();

    const int wocg = (wid & 3) * 2;          // conv3 role: oc pair base
    const int wph  = (wid >> 2) * 128;       // conv3 role: px half
    int boff[8];                             // X read base per n-frag (ushorts)
#pragma unroll
    for (int f = 0; f < 8; f++) {
        int pxl = wph + f * 16 + ln15;
        boff[f] = lg * PLSZ + ((pxl >> 5) * 34 + (pxl & 31)) * PLROW;
    }

    f32x4 acc[2][8];
#pragma unroll
    for (int o = 0; o < 2; o++)
#pragma unroll
        for (int f = 0; f < 8; f++) acc[o][f] = (f32x4)(0.f);

    // ---- main loop: per 32-ic chunk: conv1 MFMA -> X LDS -> conv3 MFMA ----
    for (int kc = 0; kc < 4; kc++) {
        // conv1: [32oc x 32K] x zin[32K x 352px]; wave handles n = wid*3..+2
        const unsigned short* w1hb = w1h + (size_t)kc * 1024 + lane * 8;
        const unsigned short* w1lb = w1l + (size_t)kc * 1024 + lane * 8;
        bf16x8 a1h0 = *(const bf16x8*)w1hb,          a1h1 = *(const bf16x8*)(w1hb + 512);
        bf16x8 a1l0 = *(const bf16x8*)w1lb,          a1l1 = *(const bf16x8*)(w1lb + 512);
        f32x4 c1[2][3];
#pragma unroll
        for (int m = 0; m < 2; m++)
#pragma unroll
            for (int ni = 0; ni < 3; ni++) c1[m][ni] = (f32x4)(0.f);
#pragma unroll
        for (int ni = 0; ni < 3; ni++) {
            int n = wid * 3 + ni;
            if (n < 22) {
                int roff = lg * PLSZ + (n * 16 + ln15) * PLROW;
                bf16x8 bh = *(const bf16x8*)(zinh + roff);
                bf16x8 bl = *(const bf16x8*)(zinl + roff);
                c1[0][ni] = __builtin_amdgcn_mfma_f32_16x16x32_bf16(a1h0, bh, c1[0][ni], 0, 0, 0);
                c1[0][ni] = __builtin_amdgcn_mfma_f32_16x16x32_bf16(a1h0, bl, c1[0][ni], 0, 0, 0);
                c1[0][ni] = __builtin_amdgcn_mfma_f32_16x16x32_bf16(a1l0, bh, c1[0][ni], 0, 0, 0);
                c1[1][ni] = __builtin_amdgcn_mfma_f32_16x16x32_bf16(a1h1, bh, c1[1][ni], 0, 0, 0);
                c1[1][ni] = __builtin_amdgcn_mfma_f32_16x16x32_bf16(a1h1, bl, c1[1][ni], 0, 0, 0);
                c1[1][ni] = __builtin_amdgcn_mfma_f32_16x16x32_bf16(a1l1, bh, c1[1][ni], 0, 0, 0);
            }
        }
        // effective bias (t folded) per (m, r)
        float eb[2][4];
#pragma unroll
        for (int m = 0; m < 2; m++)
#pragma unroll
            for (int r = 0; r < 4; r++) {
                int oc = kc * 32 + m * 16 + kl4 + r;
                eb[m][r] = b1p[oc] + t * W1t[oc * 33];
            }
        __syncthreads();   // conv3(kc-1) done reading X
        // softplus + pack + write X (border rows/cols zeroed)
#pragma unroll
        for (int ni = 0; ni < 3; ni++) {
            int n = wid * 3 + ni;
            if (n >= 22) continue;
            int ppad = n * 16 + ln15;
            if (ppad < 340) {
                int prow = ppad / 34, pcol = ppad - prow * 34;
                bool zero = (pcol == 0) || (pcol == 33) ||
                            (strip == 0 && prow == 0) || (strip == 3 && prow == 9);
#pragma unroll
                for (int m = 0; m < 2; m++) {
                    float v[4];
#pragma unroll
                    for (int r = 0; r < 4; r++)
                        v[r] = zero ? 0.f : softplus_f(c1[m][ni][r] + eb[m][r]);
                    unsigned int h01, l01, h23, l23;
                    pack2(v[0], v[1], h01, l01);
                    pack2(v[2], v[3], h23, l23);
                    int off = (m * 2 + (kl4 >> 3)) * PLSZ + ppad * PLROW + (kl4 & 7);
                    *(uint2*)(xh + off) = make_uint2(h01, h23);
                    *(uint2*)(xl + off) = make_uint2(l01, l23);
                }
            }
        }
        __syncthreads();
        // conv3 partial: 9 shifts
#pragma unroll
        for (int sh = 0; sh < 9; sh++) {
            const size_t wbase = ((size_t)(sh * 4 + kc) * 8 + wocg) * 512 + lane * 8;
            bf16x8 ah0 = *(const bf16x8*)(w2h + wbase);
            bf16x8 al0 = *(const bf16x8*)(w2l + wbase);
            bf16x8 ah1 = *(const bf16x8*)(w2h + wbase + 512);
            bf16x8 al1 = *(const bf16x8*)(w2l + wbase + 512);
            const int soff = ((sh / 3) * 34 + (sh % 3)) * PLROW;
#pragma unroll
            for (int f = 0; f < 8; f++) {
                bf16x8 bh = *(const bf16x8*)(xh + boff[f] + soff);
                bf16x8 bl = *(const bf16x8*)(xl + boff[f] + soff);
                acc[0][f] = __builtin_amdgcn_mfma_f32_16x16x32_bf16(ah0, bh, acc[0][f], 0, 0, 0);
                acc[0][f] = __builtin_amdgcn_mfma_f32_16x16x32_bf16(ah0, bl, acc[0][f], 0, 0, 0);
                acc[0][f] = __builtin_amdgcn_mfma_f32_16x16x32_bf16(al0, bh, acc[0][f], 0, 0, 0);
                acc[1][f] = __builtin_amdgcn_mfma_f32_16x16x32_bf16(ah1, bh, acc[1][f], 0, 0, 0);
                acc[1][f] = __builtin_amdgcn_mfma_f32_16x16x32_bf16(ah1, bl, acc[1][f], 0, 0, 0);
                acc[1][f] = __builtin_amdgcn_mfma_f32_16x16x32_bf16(al1, bh, acc[1][f], 0, 0, 0);
            }
        }
    }

    // ---- convw3 + RK4 epilogue, per 64-px quarter ----
    float bb2[2][4];
#pragma unroll
    for (int o2 = 0; o2 < 2; o2++)
#pragma unroll
        for (int r = 0; r < 4; r++)
            bb2[o2][r] = b2p[(wocg + o2) * 16 + kl4 + r];

    const size_t obB = (size_t)b * HCn * NPX + strip * 256;
    const int m3 = wid & 1, n4 = wid >> 1;
    float bb3[4];
#pragma unroll
    for (int r = 0; r < 4; r++) bb3[r] = b3p[m3 * 16 + kl4 + r];

#pragma unroll
    for (int q = 0; q < 4; q++) {
        __syncthreads();   // q=0: conv3 done (zin free); q>0: prev quarter read done
        if ((wid >> 2) == (q >> 1)) {      // owning px-half group writes h2 quarter
            const int fq = (q & 1) * 4;
#pragma unroll
            for (int o2 = 0; o2 < 2; o2++)
#pragma unroll
                for (int f2 = 0; f2 < 4; f2++) {
                    f32x4 a = acc[o2][fq + f2];
                    float v[4];
#pragma unroll
                    for (int r = 0; r < 4; r++) v[r] = softplus_f(a[r] + bb2[o2][r]);
                    unsigned int h01, l01, h23, l23;
                    pack2(v[0], v[1], h01, l01);
                    pack2(v[2], v[3], h23, l23);
                    int off = (f2 * 16 + ln15) * H2P + (wocg + o2) * 16 + kl4;
                    *(uint2*)(h2qh + off) = make_uint2(h01, h23);
                    *(uint2*)(h2ql + off) = make_uint2(l01, l23);
                }
        }
        __syncthreads();
        // convw3: [32st x 128K] x h2q[128K x 64px]; 1 tile per wave
        f32x4 c3 = (f32x4)(0.f);
#pragma unroll
        for (int kk = 0; kk < 4; kk++) {
            const unsigned short* a3hb = w3h + (size_t)(m3 * 4 + kk) * 512 + lane * 8;
            const unsigned short* a3lb = w3l + (size_t)(m3 * 4 + kk) * 512 + lane * 8;
            bf16x8 a3h = *(const bf16x8*)a3hb;
            bf16x8 a3l = *(const bf16x8*)a3lb;
            bf16x8 bh = *(const bf16x8*)(h2qh + (n4 * 16 + ln15) * H2P + kk * 32 + kl8);
            bf16x8 bl = *(const bf16x8*)(h2ql + (n4 * 16 + ln15) * H2P + kk * 32 + kl8);
            c3 = __builtin_amdgcn_mfma_f32_16x16x32_bf16(a3h, bh, c3, 0, 0, 0);
            c3 = __builtin_amdgcn_mfma_f32_16x16x32_bf16(a3h, bl, c3, 0, 0, 0);
            c3 = __builtin_amdgcn_mfma_f32_16x16x32_bf16(a3l, bh, c3, 0, 0, 0);
        }
#pragma unroll
        for (int r = 0; r < 4; r++) {
            int st = m3 * 16 + kl4 + r;
            float v = tanh_fast(c3[r] + bb3[r]);
            size_t i = obB + (size_t)st * NPX + q * 64 + n4 * 16 + ln15;
            if (mode == 0)      { kb_out[i] = v; accb[i] = v; }
            else if (mode == 1) { kb_out[i] = v; accb[i] += 2.f * v; }
            else                { z_out[i] = z_in[i] + (accb[i] + v) * (1.f / 6.f); }
        }
    }
}

// ---------------- readout ----------------
__global__ __launch_bounds__(256) void k_logits(
    const float* __restrict__ z, const float* __restrict__ roW,
    const float* __restrict__ rob, float* __restrict__ logits)
{
    const int b = blockIdx.x, tid = threadIdx.x;
    float p[NCLS];
#pragma unroll
    for (int c = 0; c < NCLS; c++) p[c] = 0.f;
    const float* zp = z + (size_t)b * 32768;
    for (int i = tid; i < 32768; i += 256) {
        float zv = zp[i];
#pragma unroll
        for (int c = 0; c < NCLS; c++) p[c] = fmaf(zv, roW[(size_t)c * 32768 + i], p[c]);
    }
#pragma unroll
    for (int c = 0; c < NCLS; c++)
        for (int off = 32; off > 0; off >>= 1) p[c] += __shfl_down(p[c], off, 64);
    __shared__ float red[4][NCLS];
    int wid = tid >> 6, lane = tid & 63;
    if (lane == 0)
#pragma unroll
        for (int c = 0; c < NCLS; c++) red[wid][c] = p[c];
    __syncthreads();
    if (tid < NCLS) {
        float s = red[0][tid] + red[1][tid] + red[2][tid] + red[3][tid] + rob[tid];
        logits[b * NCLS + tid] = s;
    }
}

// ---------------- loss + accuracy ----------------
__global__ __launch_bounds__(128) void k_loss(
    const float* __restrict__ logits, const int* __restrict__ y,
    float* __restrict__ out)
{
    const int b = threadIdx.x;   // 0..127
    float l[NCLS];
#pragma unroll
    for (int c = 0; c < NCLS; c++) l[c] = logits[b * NCLS + c];
    float m = l[0]; int am = 0;
#pragma unroll
    for (int c = 1; c < NCLS; c++) if (l[c] > m) { m = l[c]; am = c; }
    float s = 0.f;
#pragma unroll
    for (int c = 0; c < NCLS; c++) s += expf(l[c] - m);
    float lse = m + logf(s);
    int yy = y[b];
    float loss_b = lse - l[yy];
    float corr = (am == yy) ? 1.f : 0.f;
    for (int off = 32; off > 0; off >>= 1) {
        loss_b += __shfl_down(loss_b, off, 64);
        corr   += __shfl_down(corr,   off, 64);
    }
    __shared__ float sl[2], sc[2];
    if ((b & 63) == 0) { sl[b >> 6] = loss_b; sc[b >> 6] = corr; }
    __syncthreads();
    if (b == 0) {
        out[0] = (sl[0] + sl[1]) / (float)BN;
        out[1] = sc[0] + sc[1];
    }
}

extern "C" void kernel_launch(void* const* d_in, const int* in_sizes, int n_in,
                              void* d_out, int out_size, void* d_ws, size_t ws_size,
                              hipStream_t stream) {
    const float* x   = (const float*)d_in[0];
    const int*   y   = (const int*)  d_in[1];
    const float* aW  = (const float*)d_in[2];
    const float* ab  = (const float*)d_in[3];
    const float* W1  = (const float*)d_in[4];
    const float* b1  = (const float*)d_in[5];
    const float* W2  = (const float*)d_in[6];
    const float* b2  = (const float*)d_in[7];
    const float* W3  = (const float*)d_in[8];
    const float* b3  = (const float*)d_in[9];
    const float* roW = (const float*)d_in[10];
    const float* rob = (const float*)d_in[11];
    float* out = (float*)d_out;
    float* ws  = (float*)d_ws;

    const size_t ZSZ = (size_t)BN * HCn * NPX;    // 4.19M floats
    float* zb0    = ws;
    float* zb1    = zb0 + ZSZ;
    float* kb0    = zb1 + ZSZ;
    float* kb1    = kb0 + ZSZ;
    float* accb   = kb1 + ZSZ;
    float* logits = accb + ZSZ;
    unsigned short* w2h = (unsigned short*)(logits + 4096);
    unsigned short* w2l = w2h + 589824;
    unsigned short* w1h = w2l + 589824;
    unsigned short* w1l = w1h + 16384;
    unsigned short* w3h = w1l + 16384;
    unsigned short* w3l = w3h + 16384;

    k_packW2<<<2304, 256, 0, stream>>>(W2, w2h, w2l);
    k_packW1<<<64, 256, 0, stream>>>(W1, w1h, w1l);
    k_packW3<<<64, 256, 0, stream>>>(W3, w3h, w3l);
    k_aug<<<BN, 256, 0, stream>>>(x, aW, ab, zb0);

    float* zA = zb0;
    float* zB = zb1;
    for (int p = 0; p < PN; p++) {
        for (int e = 0; e < 4; e++) {
            const int idx = (e == 3 && p + 1 < PN) ? p + 1 : p;
            const float t = (float)p + (e == 0 ? 0.f : (e == 3 ? 1.f : 0.5f));
            const float alpha = (e == 0) ? 0.f : (e == 3 ? 1.f : 0.5f);
            const int mode = (e == 0) ? 0 : (e == 3 ? 2 : 1);
            const float* kbin = (e == 2) ? kb1 : kb0;   // e1:kb0 e2:kb1 e3:kb0
            float* kbout = (e == 1) ? kb1 : kb0;        // e0:kb0 e1:kb1 e2:kb0
            k_fused<<<dim3(4, BN), 512, 0, stream>>>(
                zA, kbin, alpha,
                b1 + (size_t)idx * HHCn, W1 + (size_t)idx * HHCn * 33, t,
                w1h + (size_t)idx * 4096, w1l + (size_t)idx * 4096,
                w2h + (size_t)idx * 147456, w2l + (size_t)idx * 147456,
                b2 + (size_t)idx * HHCn,
                w3h + (size_t)idx * 4096, w3l + (size_t)idx * 4096,
                b3 + (size_t)idx * HCn,
                kbout, accb, zB, mode);
        }
        float* tmp = zA; zA = zB; zB = tmp;
    }

    k_logits<<<BN, 256, 0, stream>>>(zA, roW, rob, logits);
    k_loss<<<1, 128, 0, stream>>>(logits, y, out);
}

// Round 8
// 1998.392 us; speedup vs baseline: 7.5151x; 1.0902x over previous
//
#include <hip/hip_runtime.h>
#include <hip/hip_bf16.h>
#include <math.h>

// Problem constants
#define BN   128      // batch
#define CIN  3
#define HCn  32       // hidden channels (ODE state)
#define HHCn 128      // inner hidden channels
#define NPX  1024     // 32*32
#define PN   4        // pieces
#define NCLS 10

// 4-row strip geometry: 8 strips/image, padded rows = 6, padded px = 6*34 = 204
// (rounded to 208 = 13 n-tiles of 16). LDS planes: 8 ic x 16B rows.
#define PPAD  204
#define PPADR 208
#define NT    13
#define PLROW 8       // ushorts per plane row (8 ic)
#define PLSZ  1664    // 208 * 8 ushorts per plane
#define H2P   136     // h2 quarter pitch (ushorts): 272B rows

typedef short bf16x8 __attribute__((ext_vector_type(8)));
typedef float f32x4  __attribute__((ext_vector_type(4)));

// ---- fast transcendentals (HW v_exp/v_log/v_rcp; err ~1e-7, threshold 0.2) ----
__device__ __forceinline__ float softplus_f(float x) {
    return fmaxf(x, 0.f) + __logf(1.f + __expf(-fabsf(x)));
}
__device__ __forceinline__ float tanh_fast(float x) {
    float e = __expf(-2.f * fabsf(x));
    float r = 1.f - 2.f * e * __builtin_amdgcn_rcpf(1.f + e);   // tanh(|x|)
    unsigned u = (__float_as_uint(r) & 0x7fffffffu) | (__float_as_uint(x) & 0x80000000u);
    return __uint_as_float(u);
}
__device__ __forceinline__ unsigned int f2bf(float f) {   // RNE fp32->bf16 bits
    unsigned int u = __float_as_uint(f);
    return (u + 0x7fffu + ((u >> 16) & 1u)) >> 16;
}
__device__ __forceinline__ float bf2f(unsigned int h) {
    return __uint_as_float(h << 16);
}
// hi/lo bf16 split of two floats via v_cvt_pk_bf16_f32 (compiler-emitted)
__device__ __forceinline__ void pack2(float a, float b, unsigned int& hi, unsigned int& lo) {
    __hip_bfloat162 h2 = __float22bfloat162_rn(float2{a, b});
    unsigned int h = *reinterpret_cast<unsigned int*>(&h2);
    float ha = __uint_as_float(h << 16);
    float hb = __uint_as_float(h & 0xffff0000u);
    __hip_bfloat162 l2 = __float22bfloat162_rn(float2{a - ha, b - hb});
    hi = h;
    lo = *reinterpret_cast<unsigned int*>(&l2);
}

// ---------------- augment: z = x * aug_W^T + aug_b ----------------
__global__ __launch_bounds__(256) void k_aug(
    const float* __restrict__ x, const float* __restrict__ aW,
    const float* __restrict__ ab, float* __restrict__ z)
{
    const int b = blockIdx.x, tid = threadIdx.x;
    const size_t xb = (size_t)b * CIN * NPX;
    const size_t zb = (size_t)b * HCn * NPX;
    float xv[CIN][4];
#pragma unroll
    for (int c = 0; c < CIN; c++)
#pragma unroll
        for (int j = 0; j < 4; j++)
            xv[c][j] = x[xb + c * NPX + tid + 256 * j];
    for (int o = 0; o < HCn; o++) {
        float w0 = aW[o * 3], w1 = aW[o * 3 + 1], w2 = aW[o * 3 + 2], bb = ab[o];
#pragma unroll
        for (int j = 0; j < 4; j++) {
            float v = fmaf(w0, xv[0][j], fmaf(w1, xv[1][j], fmaf(w2, xv[2][j], bb)));
            z[zb + (size_t)o * NPX + tid + 256 * j] = v;
        }
    }
}

// ---------------- pack W2 into MFMA A-frag order, bf16 hi/lo ----------------
__global__ __launch_bounds__(256) void k_packW2(
    const float* __restrict__ W2, unsigned short* __restrict__ whi,
    unsigned short* __restrict__ wlo)
{
    int t = blockIdx.x * 256 + threadIdx.x;          // < 589824
    int j    = t & 7;
    int lane = (t >> 3) & 63;
    int ocg  = (t >> 9) & 7;
    int kc   = (t >> 12) & 3;
    int p9s  = t >> 14;                              // p*9 + sh
    int sh = p9s % 9, p = p9s / 9;
    int dy = sh / 3, dx = sh % 3;
    int oc = ocg * 16 + (lane & 15);
    int ic = kc * 32 + (lane >> 4) * 8 + j;
    float v = W2[((((size_t)p * HHCn + oc) * HHCn + ic) * 3 + dy) * 3 + dx];
    unsigned int hi = f2bf(v);
    whi[t] = (unsigned short)hi;
    wlo[t] = (unsigned short)f2bf(v - bf2f(hi));
}

// ---------------- pack W1 (skip t-col): [p][kc][m][lane][j] -----------------
__global__ __launch_bounds__(256) void k_packW1(
    const float* __restrict__ W1, unsigned short* __restrict__ whi,
    unsigned short* __restrict__ wlo)
{
    int t = blockIdx.x * 256 + threadIdx.x;          // < 16384
    int j = t & 7, lane = (t >> 3) & 63, m = (t >> 9) & 1, kc = (t >> 10) & 3, p = t >> 12;
    int oc = kc * 32 + m * 16 + (lane & 15);
    int ic = (lane >> 4) * 8 + j;
    float v = W1[((size_t)p * HHCn + oc) * 33 + 1 + ic];
    unsigned int hi = f2bf(v);
    whi[t] = (unsigned short)hi;
    wlo[t] = (unsigned short)f2bf(v - bf2f(hi));
}

// ---------------- pack W3: [p][m][kk][lane][j] ------------------------------
__global__ __launch_bounds__(256) void k_packW3(
    const float* __restrict__ W3, unsigned short* __restrict__ whi,
    unsigned short* __restrict__ wlo)
{
    int t = blockIdx.x * 256 + threadIdx.x;          // < 16384
    int j = t & 7, lane = (t >> 3) & 63, kk = (t >> 9) & 3, m = (t >> 11) & 1, p = t >> 12;
    int st = m * 16 + (lane & 15);
    int ic = kk * 32 + (lane >> 4) * 8 + j;
    float v = W3[((size_t)p * HCn + st) * HHCn + ic];
    unsigned int hi = f2bf(v);
    whi[t] = (unsigned short)hi;
    wlo[t] = (unsigned short)f2bf(v - bf2f(hi));
}

// ---------------- fused f-eval: conv1 -> conv3x3 -> convw3 + RK4 ------------
// grid (8 strips of 4 rows, BN), 512 thr (8 waves). 52KB LDS -> 2 blocks/CU;
// __launch_bounds__(512,4) caps VGPR at 128 so occupancy holds.
__global__ __launch_bounds__(512, 4) void k_fused(
    const float* __restrict__ z_in, const float* __restrict__ kb_in, float alpha,
    const float* __restrict__ b1p, const float* __restrict__ W1t, float t,
    const unsigned short* __restrict__ w1h, const unsigned short* __restrict__ w1l,
    const unsigned short* __restrict__ w2h, const unsigned short* __restrict__ w2l,
    const float* __restrict__ b2p,
    const unsigned short* __restrict__ w3h, const unsigned short* __restrict__ w3l,
    const float* __restrict__ b3p,
    float* __restrict__ kb_out, float* __restrict__ accb, float* __restrict__ z_out,
    int mode)
{
    const int strip = blockIdx.x, b = blockIdx.y;
    const int tid = threadIdx.x, lane = tid & 63, wid = tid >> 6;
    const int ln15 = lane & 15, lg = lane >> 4;
    const int kl8 = lg * 8, kl4 = lg * 4;

    __shared__ __align__(16) unsigned short S[26624];   // 53.2 KB
    unsigned short* zinh = S;                            // 4 planes * 1664
    unsigned short* zinl = S + 6656;
    unsigned short* xh   = S + 13312;
    unsigned short* xl   = S + 19968;
    unsigned short* h2qh = S;                            // alias (zin/x freed)
    unsigned short* h2ql = S + 8704;                     // 64*136

    const size_t zbB = (size_t)b * HCn * NPX;
    const int strip0 = strip * 4;

    // ---- phase 0: stage zin = bf16hl(z + alpha*k), 32ic x 204 padded px ----
    {
        const int ic0 = wid * 4;                 // 4 ic per wave
        const int pl  = wid >> 1;                // target plane
        const int sl  = (wid & 1) * 4;           // ushort slot in 8-ush row
#pragma unroll
        for (int it = 0; it < 4; it++) {
            int ppad = it * 64 + lane;
            int prow = ppad / 34, pcol = ppad - prow * 34;
            int gy = strip0 + prow - 1, gx = pcol - 1;
            bool okm = (ppad < PPAD) && (gy >= 0) && (gy < 32) && (gx >= 0) && (gx < 32);
            int gsrc = gy * 32 + gx;
            float v[4];
#pragma unroll
            for (int c = 0; c < 4; c++)
                v[c] = okm ? z_in[zbB + (size_t)(ic0 + c) * NPX + gsrc] : 0.f;
            if (alpha != 0.f) {
#pragma unroll
                for (int c = 0; c < 4; c++)
                    if (okm) v[c] = fmaf(alpha, kb_in[zbB + (size_t)(ic0 + c) * NPX + gsrc], v[c]);
            }
            unsigned int h01, l01, h23, l23;
            pack2(v[0], v[1], h01, l01);
            pack2(v[2], v[3], h23, l23);
            if (ppad < PPADR) {
                int off = pl * PLSZ + ppad * PLROW + sl;
                *(uint2*)(zinh + off) = make_uint2(h01, h23);
                *(uint2*)(zinl + off) = make_uint2(l01, l23);
            }
        }
    }
    __syncthreads();

    const int wocg = (wid & 3) * 2;          // conv3 role: oc pair base (16-oc units)
    const int wph  = (wid >> 2) * 64;        // conv3 role: px half (64 px)
    int boff[4];                             // X read base per n-frag (ushorts)
#pragma unroll
    for (int f = 0; f < 4; f++) {
        int pxl = wph + f * 16 + ln15;
        boff[f] = lg * PLSZ + ((pxl >> 5) * 34 + (pxl & 31)) * PLROW;
    }

    f32x4 acc[2][4];
#pragma unroll
    for (int o = 0; o < 2; o++)
#pragma unroll
        for (int f = 0; f < 4; f++) acc[o][f] = (f32x4)(0.f);

    // ---- main loop: per 32-ic chunk: conv1 MFMA -> X LDS -> conv3 MFMA ----
    for (int kc = 0; kc < 4; kc++) {
        // conv1: [32oc x 32K] x zin[32K x 208px]; 13 n-tiles: n = wid + 8*ni
        const unsigned short* w1hb = w1h + (size_t)kc * 1024 + lane * 8;
        const unsigned short* w1lb = w1l + (size_t)kc * 1024 + lane * 8;
        bf16x8 a1h0 = *(const bf16x8*)w1hb,          a1h1 = *(const bf16x8*)(w1hb + 512);
        bf16x8 a1l0 = *(const bf16x8*)w1lb,          a1l1 = *(const bf16x8*)(w1lb + 512);
        f32x4 c1[2][2];
#pragma unroll
        for (int m = 0; m < 2; m++)
#pragma unroll
            for (int ni = 0; ni < 2; ni++) c1[m][ni] = (f32x4)(0.f);
#pragma unroll
        for (int ni = 0; ni < 2; ni++) {
            int n = wid + 8 * ni;
            if (ni == 0 || wid < 5) {
                int roff = lg * PLSZ + (n * 16 + ln15) * PLROW;
                bf16x8 bh = *(const bf16x8*)(zinh + roff);
                bf16x8 bl = *(const bf16x8*)(zinl + roff);
                c1[0][ni] = __builtin_amdgcn_mfma_f32_16x16x32_bf16(a1h0, bh, c1[0][ni], 0, 0, 0);
                c1[0][ni] = __builtin_amdgcn_mfma_f32_16x16x32_bf16(a1h0, bl, c1[0][ni], 0, 0, 0);
                c1[0][ni] = __builtin_amdgcn_mfma_f32_16x16x32_bf16(a1l0, bh, c1[0][ni], 0, 0, 0);
                c1[1][ni] = __builtin_amdgcn_mfma_f32_16x16x32_bf16(a1h1, bh, c1[1][ni], 0, 0, 0);
                c1[1][ni] = __builtin_amdgcn_mfma_f32_16x16x32_bf16(a1h1, bl, c1[1][ni], 0, 0, 0);
                c1[1][ni] = __builtin_amdgcn_mfma_f32_16x16x32_bf16(a1l1, bh, c1[1][ni], 0, 0, 0);
            }
        }
        // effective bias (t folded) per (m, r)
        float eb[2][4];
#pragma unroll
        for (int m = 0; m < 2; m++)
#pragma unroll
            for (int r = 0; r < 4; r++) {
                int oc = kc * 32 + m * 16 + kl4 + r;
                eb[m][r] = b1p[oc] + t * W1t[oc * 33];
            }
        __syncthreads();   // conv3(kc-1) done reading X
        // softplus + pack + write X (out-of-image rows/cols zeroed)
#pragma unroll
        for (int ni = 0; ni < 2; ni++) {
            int n = wid + 8 * ni;
            if (ni == 0 || wid < 5) {
                int ppad = n * 16 + ln15;
                int prow = ppad / 34, pcol = ppad - prow * 34;
                int gy = strip0 + prow - 1;
                bool zero = (pcol == 0) || (pcol == 33) || (gy < 0) || (gy >= 32);
#pragma unroll
                for (int m = 0; m < 2; m++) {
                    float v[4];
#pragma unroll
                    for (int r = 0; r < 4; r++)
                        v[r] = zero ? 0.f : softplus_f(c1[m][ni][r] + eb[m][r]);
                    unsigned int h01, l01, h23, l23;
                    pack2(v[0], v[1], h01, l01);
                    pack2(v[2], v[3], h23, l23);
                    int off = (m * 2 + (kl4 >> 3)) * PLSZ + ppad * PLROW + (kl4 & 7);
                    *(uint2*)(xh + off) = make_uint2(h01, h23);
                    *(uint2*)(xl + off) = make_uint2(l01, l23);
                }
            }
        }
        __syncthreads();
        // conv3 partial: 9 shifts
#pragma unroll
        for (int sh = 0; sh < 9; sh++) {
            const size_t wbase = ((size_t)(sh * 4 + kc) * 8 + wocg) * 512 + lane * 8;
            bf16x8 ah0 = *(const bf16x8*)(w2h + wbase);
            bf16x8 al0 = *(const bf16x8*)(w2l + wbase);
            bf16x8 ah1 = *(const bf16x8*)(w2h + wbase + 512);
            bf16x8 al1 = *(const bf16x8*)(w2l + wbase + 512);
            const int soff = ((sh / 3) * 34 + (sh % 3)) * PLROW;
#pragma unroll
            for (int f = 0; f < 4; f++) {
                bf16x8 bh = *(const bf16x8*)(xh + boff[f] + soff);
                bf16x8 bl = *(const bf16x8*)(xl + boff[f] + soff);
                acc[0][f] = __builtin_amdgcn_mfma_f32_16x16x32_bf16(ah0, bh, acc[0][f], 0, 0, 0);
                acc[0][f] = __builtin_amdgcn_mfma_f32_16x16x32_bf16(ah0, bl, acc[0][f], 0, 0, 0);
                acc[0][f] = __builtin_amdgcn_mfma_f32_16x16x32_bf16(al0, bh, acc[0][f], 0, 0, 0);
                acc[1][f] = __builtin_amdgcn_mfma_f32_16x16x32_bf16(ah1, bh, acc[1][f], 0, 0, 0);
                acc[1][f] = __builtin_amdgcn_mfma_f32_16x16x32_bf16(ah1, bl, acc[1][f], 0, 0, 0);
                acc[1][f] = __builtin_amdgcn_mfma_f32_16x16x32_bf16(al1, bh, acc[1][f], 0, 0, 0);
            }
        }
    }

    // ---- convw3 + RK4 epilogue, per 64-px half ----
    float bb2[2][4];
#pragma unroll
    for (int o2 = 0; o2 < 2; o2++)
#pragma unroll
        for (int r = 0; r < 4; r++)
            bb2[o2][r] = b2p[(wocg + o2) * 16 + kl4 + r];

    const size_t obB = (size_t)b * HCn * NPX + strip * 128;
    const int m3 = wid & 1, n4 = wid >> 1;
    float bb3[4];
#pragma unroll
    for (int r = 0; r < 4; r++) bb3[r] = b3p[m3 * 16 + kl4 + r];

#pragma unroll
    for (int q = 0; q < 2; q++) {
        __syncthreads();   // q=0: conv3 done (zin/X free); q=1: prev half read done
        if ((wid >> 2) == q) {             // owning px-half group writes h2 half
#pragma unroll
            for (int o2 = 0; o2 < 2; o2++)
#pragma unroll
                for (int f2 = 0; f2 < 4; f2++) {
                    f32x4 a = acc[o2][f2];
                    float v[4];
#pragma unroll
                    for (int r = 0; r < 4; r++) v[r] = softplus_f(a[r] + bb2[o2][r]);
                    unsigned int h01, l01, h23, l23;
                    pack2(v[0], v[1], h01, l01);
                    pack2(v[2], v[3], h23, l23);
                    int off = (f2 * 16 + ln15) * H2P + (wocg + o2) * 16 + kl4;
                    *(uint2*)(h2qh + off) = make_uint2(h01, h23);
                    *(uint2*)(h2ql + off) = make_uint2(l01, l23);
                }
        }
        __syncthreads();
        // convw3: [32st x 128K] x h2q[128K x 64px]; 1 tile per wave
        f32x4 c3 = (f32x4)(0.f);
#pragma unroll
        for (int kk = 0; kk < 4; kk++) {
            const unsigned short* a3hb = w3h + (size_t)(m3 * 4 + kk) * 512 + lane * 8;
            const unsigned short* a3lb = w3l + (size_t)(m3 * 4 + kk) * 512 + lane * 8;
            bf16x8 a3h = *(const bf16x8*)a3hb;
            bf16x8 a3l = *(const bf16x8*)a3lb;
            bf16x8 bh = *(const bf16x8*)(h2qh + (n4 * 16 + ln15) * H2P + kk * 32 + kl8);
            bf16x8 bl = *(const bf16x8*)(h2ql + (n4 * 16 + ln15) * H2P + kk * 32 + kl8);
            c3 = __builtin_amdgcn_mfma_f32_16x16x32_bf16(a3h, bh, c3, 0, 0, 0);
            c3 = __builtin_amdgcn_mfma_f32_16x16x32_bf16(a3h, bl, c3, 0, 0, 0);
            c3 = __builtin_amdgcn_mfma_f32_16x16x32_bf16(a3l, bh, c3, 0, 0, 0);
        }
#pragma unroll
        for (int r = 0; r < 4; r++) {
            int st = m3 * 16 + kl4 + r;
            float v = tanh_fast(c3[r] + bb3[r]);
            size_t i = obB + (size_t)st * NPX + q * 64 + n4 * 16 + ln15;
            if (mode == 0)      { kb_out[i] = v; accb[i] = v; }
            else if (mode == 1) { kb_out[i] = v; accb[i] += 2.f * v; }
            else                { z_out[i] = z_in[i] + (accb[i] + v) * (1.f / 6.f); }
        }
    }
}

// ---------------- readout ----------------
__global__ __launch_bounds__(256) void k_logits(
    const float* __restrict__ z, const float* __restrict__ roW,
    const float* __restrict__ rob, float* __restrict__ logits)
{
    const int b = blockIdx.x, tid = threadIdx.x;
    float p[NCLS];
#pragma unroll
    for (int c = 0; c < NCLS; c++) p[c] = 0.f;
    const float* zp = z + (size_t)b * 32768;
    for (int i = tid; i < 32768; i += 256) {
        float zv = zp[i];
#pragma unroll
        for (int c = 0; c < NCLS; c++) p[c] = fmaf(zv, roW[(size_t)c * 32768 + i], p[c]);
    }
#pragma unroll
    for (int c = 0; c < NCLS; c++)
        for (int off = 32; off > 0; off >>= 1) p[c] += __shfl_down(p[c], off, 64);
    __shared__ float red[4][NCLS];
    int wid = tid >> 6, lane = tid & 63;
    if (lane == 0)
#pragma unroll
        for (int c = 0; c < NCLS; c++) red[wid][c] = p[c];
    __syncthreads();
    if (tid < NCLS) {
        float s = red[0][tid] + red[1][tid] + red[2][tid] + red[3][tid] + rob[tid];
        logits[b * NCLS + tid] = s;
    }
}

// ---------------- loss + accuracy ----------------
__global__ __launch_bounds__(128) void k_loss(
    const float* __restrict__ logits, const int* __restrict__ y,
    float* __restrict__ out)
{
    const int b = threadIdx.x;   // 0..127
    float l[NCLS];
#pragma unroll
    for (int c = 0; c < NCLS; c++) l[c] = logits[b * NCLS + c];
    float m = l[0]; int am = 0;
#pragma unroll
    for (int c = 1; c < NCLS; c++) if (l[c] > m) { m = l[c]; am = c; }
    float s = 0.f;
#pragma unroll
    for (int c = 0; c < NCLS; c++) s += expf(l[c] - m);
    float lse = m + logf(s);
    int yy = y[b];
    float loss_b = lse - l[yy];
    float corr = (am == yy) ? 1.f : 0.f;
    for (int off = 32; off > 0; off >>= 1) {
        loss_b += __shfl_down(loss_b, off, 64);
        corr   += __shfl_down(corr,   off, 64);
    }
    __shared__ float sl[2], sc[2];
    if ((b & 63) == 0) { sl[b >> 6] = loss_b; sc[b >> 6] = corr; }
    __syncthreads();
    if (b == 0) {
        out[0] = (sl[0] + sl[1]) / (float)BN;
        out[1] = sc[0] + sc[1];
    }
}

extern "C" void kernel_launch(void* const* d_in, const int* in_sizes, int n_in,
                              void* d_out, int out_size, void* d_ws, size_t ws_size,
                              hipStream_t stream) {
    const float* x   = (const float*)d_in[0];
    const int*   y   = (const int*)  d_in[1];
    const float* aW  = (const float*)d_in[2];
    const float* ab  = (const float*)d_in[3];
    const float* W1  = (const float*)d_in[4];
    const float* b1  = (const float*)d_in[5];
    const float* W2  = (const float*)d_in[6];
    const float* b2  = (const float*)d_in[7];
    const float* W3  = (const float*)d_in[8];
    const float* b3  = (const float*)d_in[9];
    const float* roW = (const float*)d_in[10];
    const float* rob = (const float*)d_in[11];
    float* out = (float*)d_out;
    float* ws  = (float*)d_ws;

    const size_t ZSZ = (size_t)BN * HCn * NPX;    // 4.19M floats
    float* zb0    = ws;
    float* zb1    = zb0 + ZSZ;
    float* kb0    = zb1 + ZSZ;
    float* kb1    = kb0 + ZSZ;
    float* accb   = kb1 + ZSZ;
    float* logits = accb + ZSZ;
    unsigned short* w2h = (unsigned short*)(logits + 4096);
    unsigned short* w2l = w2h + 589824;
    unsigned short* w1h = w2l + 589824;
    unsigned short* w1l = w1h + 16384;
    unsigned short* w3h = w1l + 16384;
    unsigned short* w3l = w3h + 16384;

    k_packW2<<<2304, 256, 0, stream>>>(W2, w2h, w2l);
    k_packW1<<<64, 256, 0, stream>>>(W1, w1h, w1l);
    k_packW3<<<64, 256, 0, stream>>>(W3, w3h, w3l);
    k_aug<<<BN, 256, 0, stream>>>(x, aW, ab, zb0);

    float* zA = zb0;
    float* zB = zb1;
    for (int p = 0; p < PN; p++) {
        for (int e = 0; e < 4; e++) {
            const int idx = (e == 3 && p + 1 < PN) ? p + 1 : p;
            const float t = (float)p + (e == 0 ? 0.f : (e == 3 ? 1.f : 0.5f));
            const float alpha = (e == 0) ? 0.f : (e == 3 ? 1.f : 0.5f);
            const int mode = (e == 0) ? 0 : (e == 3 ? 2 : 1);
            const float* kbin = (e == 2) ? kb1 : kb0;   // e1:kb0 e2:kb1 e3:kb0
            float* kbout = (e == 1) ? kb1 : kb0;        // e0:kb0 e1:kb1 e2:kb0
            k_fused<<<dim3(8, BN), 512, 0, stream>>>(
                zA, kbin, alpha,
                b1 + (size_t)idx * HHCn, W1 + (size_t)idx * HHCn * 33, t,
                w1h + (size_t)idx * 4096, w1l + (size_t)idx * 4096,
                w2h + (size_t)idx * 147456, w2l + (size_t)idx * 147456,
                b2 + (size_t)idx * HHCn,
                w3h + (size_t)idx * 4096, w3l + (size_t)idx * 4096,
                b3 + (size_t)idx * HCn,
                kbout, accb, zB, mode);
        }
        float* tmp = zA; zA = zB; zB = tmp;
    }

    k_logits<<<BN, 256, 0, stream>>>(zA, roW, rob, logits);
    k_loss<<<1, 128, 0, stream>>>(logits, y, out);
}

// Round 9
// 1992.037 us; speedup vs baseline: 7.5390x; 1.0032x over previous
//
#include <hip/hip_runtime.h>
#include <hip/hip_bf16.h>
#include <math.h>

// Problem constants
#define BN   128      // batch
#define CIN  3
#define HCn  32       // hidden channels (ODE state)
#define HHCn 128      // inner hidden channels
#define NPX  1024     // 32*32
#define PN   4        // pieces
#define NCLS 10

// 4-row strip geometry: 8 strips/image, padded px = 6*34 = 204 (rounded 208).
#define PPAD  204
#define PPADR 208
#define PLROW 8       // ushorts per plane row (8 ic)
#define PLSZ  1664    // 208 * 8 ushorts per plane
#define H2P   136     // h2 pitch (ushorts): 272B rows

typedef short bf16x8 __attribute__((ext_vector_type(8)));
typedef float f32x4  __attribute__((ext_vector_type(4)));

// ---- fast transcendentals (HW v_exp/v_log/v_rcp; err ~1e-7, threshold 0.2) ----
__device__ __forceinline__ float softplus_f(float x) {
    return fmaxf(x, 0.f) + __logf(1.f + __expf(-fabsf(x)));
}
__device__ __forceinline__ float tanh_fast(float x) {
    float e = __expf(-2.f * fabsf(x));
    float r = 1.f - 2.f * e * __builtin_amdgcn_rcpf(1.f + e);   // tanh(|x|)
    unsigned u = (__float_as_uint(r) & 0x7fffffffu) | (__float_as_uint(x) & 0x80000000u);
    return __uint_as_float(u);
}
__device__ __forceinline__ unsigned int f2bf(float f) {   // RNE fp32->bf16 bits
    unsigned int u = __float_as_uint(f);
    return (u + 0x7fffu + ((u >> 16) & 1u)) >> 16;
}
__device__ __forceinline__ float bf2f(unsigned int h) {
    return __uint_as_float(h << 16);
}
__device__ __forceinline__ void pack2(float a, float b, unsigned int& hi, unsigned int& lo) {
    __hip_bfloat162 h2 = __float22bfloat162_rn(float2{a, b});
    unsigned int h = *reinterpret_cast<unsigned int*>(&h2);
    float ha = __uint_as_float(h << 16);
    float hb = __uint_as_float(h & 0xffff0000u);
    __hip_bfloat162 l2 = __float22bfloat162_rn(float2{a - ha, b - hb});
    hi = h;
    lo = *reinterpret_cast<unsigned int*>(&l2);
}

// ---------------- augment ----------------
__global__ __launch_bounds__(256) void k_aug(
    const float* __restrict__ x, const float* __restrict__ aW,
    const float* __restrict__ ab, float* __restrict__ z)
{
    const int b = blockIdx.x, tid = threadIdx.x;
    const size_t xb = (size_t)b * CIN * NPX;
    const size_t zb = (size_t)b * HCn * NPX;
    float xv[CIN][4];
#pragma unroll
    for (int c = 0; c < CIN; c++)
#pragma unroll
        for (int j = 0; j < 4; j++)
            xv[c][j] = x[xb + c * NPX + tid + 256 * j];
    for (int o = 0; o < HCn; o++) {
        float w0 = aW[o * 3], w1 = aW[o * 3 + 1], w2 = aW[o * 3 + 2], bb = ab[o];
#pragma unroll
        for (int j = 0; j < 4; j++) {
            float v = fmaf(w0, xv[0][j], fmaf(w1, xv[1][j], fmaf(w2, xv[2][j], bb)));
            z[zb + (size_t)o * NPX + tid + 256 * j] = v;
        }
    }
}

// ---------------- pack W2 ----------------
__global__ __launch_bounds__(256) void k_packW2(
    const float* __restrict__ W2, unsigned short* __restrict__ whi,
    unsigned short* __restrict__ wlo)
{
    int t = blockIdx.x * 256 + threadIdx.x;          // < 589824
    int j    = t & 7;
    int lane = (t >> 3) & 63;
    int ocg  = (t >> 9) & 7;
    int kc   = (t >> 12) & 3;
    int p9s  = t >> 14;                              // p*9 + sh
    int sh = p9s % 9, p = p9s / 9;
    int dy = sh / 3, dx = sh % 3;
    int oc = ocg * 16 + (lane & 15);
    int ic = kc * 32 + (lane >> 4) * 8 + j;
    float v = W2[((((size_t)p * HHCn + oc) * HHCn + ic) * 3 + dy) * 3 + dx];
    unsigned int hi = f2bf(v);
    whi[t] = (unsigned short)hi;
    wlo[t] = (unsigned short)f2bf(v - bf2f(hi));
}

// ---------------- pack W1 ----------------
__global__ __launch_bounds__(256) void k_packW1(
    const float* __restrict__ W1, unsigned short* __restrict__ whi,
    unsigned short* __restrict__ wlo)
{
    int t = blockIdx.x * 256 + threadIdx.x;          // < 16384
    int j = t & 7, lane = (t >> 3) & 63, m = (t >> 9) & 1, kc = (t >> 10) & 3, p = t >> 12;
    int oc = kc * 32 + m * 16 + (lane & 15);
    int ic = (lane >> 4) * 8 + j;
    float v = W1[((size_t)p * HHCn + oc) * 33 + 1 + ic];
    unsigned int hi = f2bf(v);
    whi[t] = (unsigned short)hi;
    wlo[t] = (unsigned short)f2bf(v - bf2f(hi));
}

// ---------------- pack W3 ----------------
__global__ __launch_bounds__(256) void k_packW3(
    const float* __restrict__ W3, unsigned short* __restrict__ whi,
    unsigned short* __restrict__ wlo)
{
    int t = blockIdx.x * 256 + threadIdx.x;          // < 16384
    int j = t & 7, lane = (t >> 3) & 63, kk = (t >> 9) & 3, m = (t >> 11) & 1, p = t >> 12;
    int st = m * 16 + (lane & 15);
    int ic = kk * 32 + (lane >> 4) * 8 + j;
    float v = W3[((size_t)p * HCn + st) * HHCn + ic];
    unsigned int hi = f2bf(v);
    whi[t] = (unsigned short)hi;
    wlo[t] = (unsigned short)f2bf(v - bf2f(hi));
}

// ---------------- fused f-eval, software-pipelined with double-buffered X ---
// grid (8 strips, BN), 512 thr. Region kc: {conv1(kc+1) MFMA | pack+write
// X[(kc+1)&1] | conv3(kc) on X[kc&1]} then ONE barrier. 79.9KB LDS -> 2 blk/CU.
__global__ __launch_bounds__(512, 4) void k_fused(
    const float* __restrict__ z_in, const float* __restrict__ kb_in, float alpha,
    const float* __restrict__ b1p, const float* __restrict__ W1t, float t,
    const unsigned short* __restrict__ w1h, const unsigned short* __restrict__ w1l,
    const unsigned short* __restrict__ w2h, const unsigned short* __restrict__ w2l,
    const float* __restrict__ b2p,
    const unsigned short* __restrict__ w3h, const unsigned short* __restrict__ w3l,
    const float* __restrict__ b3p,
    float* __restrict__ kb_out, float* __restrict__ accb, float* __restrict__ z_out,
    int mode)
{
    const int strip = blockIdx.x, b = blockIdx.y;
    const int tid = threadIdx.x, lane = tid & 63, wid = tid >> 6;
    const int ln15 = lane & 15, lg = lane >> 4;
    const int kl8 = lg * 8, kl4 = lg * 4;

    __shared__ __align__(16) unsigned short S[39936];   // 79.87 KB
    unsigned short* zinh = S;                            // 6656
    unsigned short* zinl = S + 6656;
    unsigned short* xh0  = S + 13312;
    unsigned short* xl0  = S + 19968;
    unsigned short* xh1  = S + 26624;
    unsigned short* xl1  = S + 33280;
    unsigned short* h2qh = S;                            // alias zin+X0 (freed)
    unsigned short* h2ql = S + 8704;

    const size_t zbB = (size_t)b * HCn * NPX;
    const int strip0 = strip * 4;

    // ---- phase 0: stage zin = bf16hl(z + alpha*k), 32ic x 204 padded px ----
    {
        const int ic0 = wid * 4;
        const int pl  = wid >> 1;
        const int sl  = (wid & 1) * 4;
#pragma unroll
        for (int it = 0; it < 4; it++) {
            int ppad = it * 64 + lane;
            int prow = ppad / 34, pcol = ppad - prow * 34;
            int gy = strip0 + prow - 1, gx = pcol - 1;
            bool okm = (ppad < PPAD) && (gy >= 0) && (gy < 32) && (gx >= 0) && (gx < 32);
            int gsrc = gy * 32 + gx;
            float v[4];
#pragma unroll
            for (int c = 0; c < 4; c++)
                v[c] = okm ? z_in[zbB + (size_t)(ic0 + c) * NPX + gsrc] : 0.f;
            if (alpha != 0.f) {
#pragma unroll
                for (int c = 0; c < 4; c++)
                    if (okm) v[c] = fmaf(alpha, kb_in[zbB + (size_t)(ic0 + c) * NPX + gsrc], v[c]);
            }
            unsigned int h01, l01, h23, l23;
            pack2(v[0], v[1], h01, l01);
            pack2(v[2], v[3], h23, l23);
            if (ppad < PPADR) {
                int off = pl * PLSZ + ppad * PLROW + sl;
                *(uint2*)(zinh + off) = make_uint2(h01, h23);
                *(uint2*)(zinl + off) = make_uint2(l01, l23);
            }
        }
    }

    const int wocg = (wid & 3) * 2;          // conv3: oc pair base (16-oc units)
    const int wph  = (wid >> 2) * 64;        // conv3: px half (64 px)
    int boff[4];
#pragma unroll
    for (int f = 0; f < 4; f++) {
        int pxl = wph + f * 16 + ln15;
        boff[f] = lg * PLSZ + ((pxl >> 5) * 34 + (pxl & 31)) * PLROW;
    }

    f32x4 acc[2][4];
#pragma unroll
    for (int o = 0; o < 2; o++)
#pragma unroll
        for (int f = 0; f < 4; f++) acc[o][f] = (f32x4)(0.f);

    f32x4 c1[2][2];

    // conv1 MFMA for chunk kc -> c1 (reads zin; zin stable all main loop)
    auto do_conv1 = [&](int kc) {
        const unsigned short* w1hb = w1h + (size_t)kc * 1024 + lane * 8;
        const unsigned short* w1lb = w1l + (size_t)kc * 1024 + lane * 8;
        bf16x8 a1h0 = *(const bf16x8*)w1hb, a1h1 = *(const bf16x8*)(w1hb + 512);
        bf16x8 a1l0 = *(const bf16x8*)w1lb, a1l1 = *(const bf16x8*)(w1lb + 512);
#pragma unroll
        for (int m = 0; m < 2; m++)
#pragma unroll
            for (int ni = 0; ni < 2; ni++) c1[m][ni] = (f32x4)(0.f);
#pragma unroll
        for (int ni = 0; ni < 2; ni++) {
            int n = wid + 8 * ni;
            if (ni == 0 || wid < 5) {
                int roff = lg * PLSZ + (n * 16 + ln15) * PLROW;
                bf16x8 bh = *(const bf16x8*)(zinh + roff);
                bf16x8 bl = *(const bf16x8*)(zinl + roff);
                c1[0][ni] = __builtin_amdgcn_mfma_f32_16x16x32_bf16(a1h0, bh, c1[0][ni], 0, 0, 0);
                c1[0][ni] = __builtin_amdgcn_mfma_f32_16x16x32_bf16(a1h0, bl, c1[0][ni], 0, 0, 0);
                c1[0][ni] = __builtin_amdgcn_mfma_f32_16x16x32_bf16(a1l0, bh, c1[0][ni], 0, 0, 0);
                c1[1][ni] = __builtin_amdgcn_mfma_f32_16x16x32_bf16(a1h1, bh, c1[1][ni], 0, 0, 0);
                c1[1][ni] = __builtin_amdgcn_mfma_f32_16x16x32_bf16(a1h1, bl, c1[1][ni], 0, 0, 0);
                c1[1][ni] = __builtin_amdgcn_mfma_f32_16x16x32_bf16(a1l1, bh, c1[1][ni], 0, 0, 0);
            }
        }
    };

    // softplus + pack + write X chunk kc into (xh_, xl_)
    auto do_writeX = [&](int kc, unsigned short* xh_, unsigned short* xl_) {
        float eb[2][4];
#pragma unroll
        for (int m = 0; m < 2; m++)
#pragma unroll
            for (int r = 0; r < 4; r++) {
                int oc = kc * 32 + m * 16 + kl4 + r;
                eb[m][r] = b1p[oc] + t * W1t[oc * 33];
            }
#pragma unroll
        for (int ni = 0; ni < 2; ni++) {
            int n = wid + 8 * ni;
            if (ni == 0 || wid < 5) {
                int ppad = n * 16 + ln15;
                int prow = ppad / 34, pcol = ppad - prow * 34;
                int gy = strip0 + prow - 1;
                bool zero = (pcol == 0) || (pcol == 33) || (gy < 0) || (gy >= 32);
#pragma unroll
                for (int m = 0; m < 2; m++) {
                    float v[4];
#pragma unroll
                    for (int r = 0; r < 4; r++)
                        v[r] = zero ? 0.f : softplus_f(c1[m][ni][r] + eb[m][r]);
                    unsigned int h01, l01, h23, l23;
                    pack2(v[0], v[1], h01, l01);
                    pack2(v[2], v[3], h23, l23);
                    int off = (m * 2 + (kl4 >> 3)) * PLSZ + ppad * PLROW + (kl4 & 7);
                    *(uint2*)(xh_ + off) = make_uint2(h01, h23);
                    *(uint2*)(xl_ + off) = make_uint2(l01, l23);
                }
            }
        }
    };

    // conv3 partial for chunk kc from (xh_, xl_)
    auto do_conv3 = [&](int kc, const unsigned short* xh_, const unsigned short* xl_) {
#pragma unroll
        for (int sh = 0; sh < 9; sh++) {
            const size_t wbase = ((size_t)(sh * 4 + kc) * 8 + wocg) * 512 + lane * 8;
            bf16x8 ah0 = *(const bf16x8*)(w2h + wbase);
            bf16x8 al0 = *(const bf16x8*)(w2l + wbase);
            bf16x8 ah1 = *(const bf16x8*)(w2h + wbase + 512);
            bf16x8 al1 = *(const bf16x8*)(w2l + wbase + 512);
            const int soff = ((sh / 3) * 34 + (sh % 3)) * PLROW;
#pragma unroll
            for (int f = 0; f < 4; f++) {
                bf16x8 bh = *(const bf16x8*)(xh_ + boff[f] + soff);
                bf16x8 bl = *(const bf16x8*)(xl_ + boff[f] + soff);
                acc[0][f] = __builtin_amdgcn_mfma_f32_16x16x32_bf16(ah0, bh, acc[0][f], 0, 0, 0);
                acc[0][f] = __builtin_amdgcn_mfma_f32_16x16x32_bf16(ah0, bl, acc[0][f], 0, 0, 0);
                acc[0][f] = __builtin_amdgcn_mfma_f32_16x16x32_bf16(al0, bh, acc[0][f], 0, 0, 0);
                acc[1][f] = __builtin_amdgcn_mfma_f32_16x16x32_bf16(ah1, bh, acc[1][f], 0, 0, 0);
                acc[1][f] = __builtin_amdgcn_mfma_f32_16x16x32_bf16(ah1, bl, acc[1][f], 0, 0, 0);
                acc[1][f] = __builtin_amdgcn_mfma_f32_16x16x32_bf16(al1, bh, acc[1][f], 0, 0, 0);
            }
        }
    };

    __syncthreads();                 // zin staged
    do_conv1(0);
    do_writeX(0, xh0, xl0);          // X0 <- chunk 0
    __syncthreads();

    // region kc=0: conv1(1) | write X1 | conv3(0) on X0
    do_conv1(1); do_writeX(1, xh1, xl1); do_conv3(0, xh0, xl0);
    __syncthreads();
    // region kc=1: conv1(2) | write X0 | conv3(1) on X1
    do_conv1(2); do_writeX(2, xh0, xl0); do_conv3(1, xh1, xl1);
    __syncthreads();
    // region kc=2: conv1(3) | write X1 | conv3(2) on X0
    do_conv1(3); do_writeX(3, xh1, xl1); do_conv3(2, xh0, xl0);
    __syncthreads();
    // region kc=3: conv3(3) on X1
    do_conv3(3, xh1, xl1);

    // ---- convw3 + RK4 epilogue, per 64-px half ----
    float bb2[2][4];
#pragma unroll
    for (int o2 = 0; o2 < 2; o2++)
#pragma unroll
        for (int r = 0; r < 4; r++)
            bb2[o2][r] = b2p[(wocg + o2) * 16 + kl4 + r];

    const size_t obB = (size_t)b * HCn * NPX + strip * 128;
    const int m3 = wid & 1, n4 = wid >> 1;
    float bb3[4];
#pragma unroll
    for (int r = 0; r < 4; r++) bb3[r] = b3p[m3 * 16 + kl4 + r];

#pragma unroll
    for (int q = 0; q < 2; q++) {
        __syncthreads();   // q=0: conv3(3) reads done (h2 aliases zin+X0, X1 untouched)
        if ((wid >> 2) == q) {             // owning px-half group writes h2 half
#pragma unroll
            for (int o2 = 0; o2 < 2; o2++)
#pragma unroll
                for (int f2 = 0; f2 < 4; f2++) {
                    f32x4 a = acc[o2][f2];
                    float v[4];
#pragma unroll
                    for (int r = 0; r < 4; r++) v[r] = softplus_f(a[r] + bb2[o2][r]);
                    unsigned int h01, l01, h23, l23;
                    pack2(v[0], v[1], h01, l01);
                    pack2(v[2], v[3], h23, l23);
                    int off = (f2 * 16 + ln15) * H2P + (wocg + o2) * 16 + kl4;
                    *(uint2*)(h2qh + off) = make_uint2(h01, h23);
                    *(uint2*)(h2ql + off) = make_uint2(l01, l23);
                }
        }
        __syncthreads();
        // convw3: [32st x 128K] x h2q[128K x 64px]; 1 tile per wave
        f32x4 c3 = (f32x4)(0.f);
#pragma unroll
        for (int kk = 0; kk < 4; kk++) {
            const unsigned short* a3hb = w3h + (size_t)(m3 * 4 + kk) * 512 + lane * 8;
            const unsigned short* a3lb = w3l + (size_t)(m3 * 4 + kk) * 512 + lane * 8;
            bf16x8 a3h = *(const bf16x8*)a3hb;
            bf16x8 a3l = *(const bf16x8*)a3lb;
            bf16x8 bh = *(const bf16x8*)(h2qh + (n4 * 16 + ln15) * H2P + kk * 32 + kl8);
            bf16x8 bl = *(const bf16x8*)(h2ql + (n4 * 16 + ln15) * H2P + kk * 32 + kl8);
            c3 = __builtin_amdgcn_mfma_f32_16x16x32_bf16(a3h, bh, c3, 0, 0, 0);
            c3 = __builtin_amdgcn_mfma_f32_16x16x32_bf16(a3h, bl, c3, 0, 0, 0);
            c3 = __builtin_amdgcn_mfma_f32_16x16x32_bf16(a3l, bh, c3, 0, 0, 0);
        }
#pragma unroll
        for (int r = 0; r < 4; r++) {
            int st = m3 * 16 + kl4 + r;
            float v = tanh_fast(c3[r] + bb3[r]);
            size_t i = obB + (size_t)st * NPX + q * 64 + n4 * 16 + ln15;
            if (mode == 0)      { kb_out[i] = v; accb[i] = v; }
            else if (mode == 1) { kb_out[i] = v; accb[i] += 2.f * v; }
            else                { z_out[i] = z_in[i] + (accb[i] + v) * (1.f / 6.f); }
        }
    }
}

// ---------------- readout ----------------
__global__ __launch_bounds__(256) void k_logits(
    const float* __restrict__ z, const float* __restrict__ roW,
    const float* __restrict__ rob, float* __restrict__ logits)
{
    const int b = blockIdx.x, tid = threadIdx.x;
    float p[NCLS];
#pragma unroll
    for (int c = 0; c < NCLS; c++) p[c] = 0.f;
    const float* zp = z + (size_t)b * 32768;
    for (int i = tid; i < 32768; i += 256) {
        float zv = zp[i];
#pragma unroll
        for (int c = 0; c < NCLS; c++) p[c] = fmaf(zv, roW[(size_t)c * 32768 + i], p[c]);
    }
#pragma unroll
    for (int c = 0; c < NCLS; c++)
        for (int off = 32; off > 0; off >>= 1) p[c] += __shfl_down(p[c], off, 64);
    __shared__ float red[4][NCLS];
    int wid = tid >> 6, lane = tid & 63;
    if (lane == 0)
#pragma unroll
        for (int c = 0; c < NCLS; c++) red[wid][c] = p[c];
    __syncthreads();
    if (tid < NCLS) {
        float s = red[0][tid] + red[1][tid] + red[2][tid] + red[3][tid] + rob[tid];
        logits[b * NCLS + tid] = s;
    }
}

// ---------------- loss + accuracy ----------------
__global__ __launch_bounds__(128) void k_loss(
    const float* __restrict__ logits, const int* __restrict__ y,
    float* __restrict__ out)
{
    const int b = threadIdx.x;   // 0..127
    float l[NCLS];
#pragma unroll
    for (int c = 0; c < NCLS; c++) l[c] = logits[b * NCLS + c];
    float m = l[0]; int am = 0;
#pragma unroll
    for (int c = 1; c < NCLS; c++) if (l[c] > m) { m = l[c]; am = c; }
    float s = 0.f;
#pragma unroll
    for (int c = 0; c < NCLS; c++) s += expf(l[c] - m);
    float lse = m + logf(s);
    int yy = y[b];
    float loss_b = lse - l[yy];
    float corr = (am == yy) ? 1.f : 0.f;
    for (int off = 32; off > 0; off >>= 1) {
        loss_b += __shfl_down(loss_b, off, 64);
        corr   += __shfl_down(corr,   off, 64);
    }
    __shared__ float sl[2], sc[2];
    if ((b & 63) == 0) { sl[b >> 6] = loss_b; sc[b >> 6] = corr; }
    __syncthreads();
    if (b == 0) {
        out[0] = (sl[0] + sl[1]) / (float)BN;
        out[1] = sc[0] + sc[1];
    }
}

extern "C" void kernel_launch(void* const* d_in, const int* in_sizes, int n_in,
                              void* d_out, int out_size, void* d_ws, size_t ws_size,
                              hipStream_t stream) {
    const float* x   = (const float*)d_in[0];
    const int*   y   = (const int*)  d_in[1];
    const float* aW  = (const float*)d_in[2];
    const float* ab  = (const float*)d_in[3];
    const float* W1  = (const float*)d_in[4];
    const float* b1  = (const float*)d_in[5];
    const float* W2  = (const float*)d_in[6];
    const float* b2  = (const float*)d_in[7];
    const float* W3  = (const float*)d_in[8];
    const float* b3  = (const float*)d_in[9];
    const float* roW = (const float*)d_in[10];
    const float* rob = (const float*)d_in[11];
    float* out = (float*)d_out;
    float* ws  = (float*)d_ws;

    const size_t ZSZ = (size_t)BN * HCn * NPX;    // 4.19M floats
    float* zb0    = ws;
    float* zb1    = zb0 + ZSZ;
    float* kb0    = zb1 + ZSZ;
    float* kb1    = kb0 + ZSZ;
    float* accb   = kb1 + ZSZ;
    float* logits = accb + ZSZ;
    unsigned short* w2h = (unsigned short*)(logits + 4096);
    unsigned short* w2l = w2h + 589824;
    unsigned short* w1h = w2l + 589824;
    unsigned short* w1l = w1h + 16384;
    unsigned short* w3h = w1l + 16384;
    unsigned short* w3l = w3h + 16384;

    k_packW2<<<2304, 256, 0, stream>>>(W2, w2h, w2l);
    k_packW1<<<64, 256, 0, stream>>>(W1, w1h, w1l);
    k_packW3<<<64, 256, 0, stream>>>(W3, w3h, w3l);
    k_aug<<<BN, 256, 0, stream>>>(x, aW, ab, zb0);

    float* zA = zb0;
    float* zB = zb1;
    for (int p = 0; p < PN; p++) {
        for (int e = 0; e < 4; e++) {
            const int idx = (e == 3 && p + 1 < PN) ? p + 1 : p;
            const float t = (float)p + (e == 0 ? 0.f : (e == 3 ? 1.f : 0.5f));
            const float alpha = (e == 0) ? 0.f : (e == 3 ? 1.f : 0.5f);
            const int mode = (e == 0) ? 0 : (e == 3 ? 2 : 1);
            const float* kbin = (e == 2) ? kb1 : kb0;   // e1:kb0 e2:kb1 e3:kb0
            float* kbout = (e == 1) ? kb1 : kb0;        // e0:kb0 e1:kb1 e2:kb0
            k_fused<<<dim3(8, BN), 512, 0, stream>>>(
                zA, kbin, alpha,
                b1 + (size_t)idx * HHCn, W1 + (size_t)idx * HHCn * 33, t,
                w1h + (size_t)idx * 4096, w1l + (size_t)idx * 4096,
                w2h + (size_t)idx * 147456, w2l + (size_t)idx * 147456,
                b2 + (size_t)idx * HHCn,
                w3h + (size_t)idx * 4096, w3l + (size_t)idx * 4096,
                b3 + (size_t)idx * HCn,
                kbout, accb, zB, mode);
        }
        float* tmp = zA; zA = zB; zB = tmp;
    }

    k_logits<<<BN, 256, 0, stream>>>(zA, roW, rob, logits);
    k_loss<<<1, 128, 0, stream>>>(logits, y, out);
}